// Round 2
// baseline (3120.554 us; speedup 1.0000x reference)
//
#include <hip/hip_runtime.h>
#include <cstdint>
#include <cstddef>

constexpr int N_  = 20480;
constexpr int E_  = 163840;
constexpr int G_  = 512;
constexpr int D_  = 128;
constexpr int H_  = 4;
constexpr int R_  = 8;
constexpr int L_  = 4;
constexpr int HK_ = 512;   // H*D
constexpr int NPG_ = N_ / G_; // 40

// ---------------- zero helpers ----------------
__global__ void k_zero_i(int* __restrict__ p, int n) {
  int i = blockIdx.x * blockDim.x + threadIdx.x;
  if (i < n) p[i] = 0;
}
__global__ void k_zero_f(float* __restrict__ p, int n) {
  int i = blockIdx.x * blockDim.x + threadIdx.x;
  if (i < n) p[i] = 0.f;
}

// ---------------- CSR build (edges sorted by dst) ----------------
__global__ void k_count(const int* __restrict__ dst, int* __restrict__ counts) {
  int e = blockIdx.x * blockDim.x + threadIdx.x;
  if (e < E_) atomicAdd(&counts[dst[e]], 1);
}

__global__ void k_scan(const int* __restrict__ counts, int* __restrict__ indptr,
                       int* __restrict__ cursor) {
  __shared__ int part[256];
  __shared__ int offs[257];
  int t = threadIdx.x;
  const int per = N_ / 256; // 80
  int base = t * per;
  int s = 0;
  for (int i = 0; i < per; ++i) s += counts[base + i];
  part[t] = s;
  __syncthreads();
  if (t == 0) {
    offs[0] = 0;
    for (int i = 0; i < 256; ++i) offs[i + 1] = offs[i] + part[i];
  }
  __syncthreads();
  int run = offs[t];
  for (int i = 0; i < per; ++i) {
    indptr[base + i] = run;
    cursor[base + i] = run;
    run += counts[base + i];
  }
  if (t == 255) indptr[N_] = run;
}

__global__ void k_scatter(const int* __restrict__ dst, int* __restrict__ cursor,
                          int* __restrict__ esort) {
  int e = blockIdx.x * blockDim.x + threadIdx.x;
  if (e < E_) {
    int p = atomicAdd(&cursor[dst[e]], 1);
    esort[p] = e;
  }
}

// ---------------- embedding lookup ----------------
__global__ void k_embed(const int* __restrict__ xn, const float* __restrict__ emb,
                        float* __restrict__ x) {
  int i = blockIdx.x * blockDim.x + threadIdx.x;
  if (i < N_ * D_) {
    int n = i >> 7, d = i & 127;
    x[i] = emb[xn[n] * D_ + d];
  }
}

// ---------------- WQ[r,d,h] = sum_k W[r,d,k] Q[k,h] (and WK) ----------------
__global__ void k_wqk(const float* __restrict__ Wl, const float* __restrict__ Ql,
                      const float* __restrict__ Kl, float* __restrict__ WQ,
                      float* __restrict__ WK) {
  int i = blockIdx.x * blockDim.x + threadIdx.x; // R*D*H = 4096
  if (i >= R_ * D_ * H_) return;
  int h = i & 3, d = (i >> 2) & 127, r = i >> 9;
  const float* wrow = Wl + ((size_t)r * D_ + d) * HK_;
  float sq = 0.f, sk = 0.f;
  for (int k = 0; k < HK_; ++k) {
    float w = wrow[k];
    sq += w * Ql[k * H_ + h];
    sk += w * Kl[k * H_ + h];
  }
  WQ[i] = sq;
  WK[i] = sk;
}

// ---------------- q[n,r,h] = x[n,:] . WQ[r,:,h] ----------------
__global__ void k_qk(const float* __restrict__ x, const float* __restrict__ WQ,
                     const float* __restrict__ WK, float* __restrict__ q,
                     float* __restrict__ kk) {
  int i = blockIdx.x * blockDim.x + threadIdx.x; // N*R*H
  if (i >= N_ * R_ * H_) return;
  int h = i & 3, r = (i >> 2) & 7, n = i >> 5;
  const float* xr = x + (size_t)n * D_;
  const float* wq = WQ + ((size_t)r * D_) * H_ + h;
  const float* wk = WK + ((size_t)r * D_) * H_ + h;
  float sq = 0.f, sk = 0.f;
  for (int d = 0; d < D_; ++d) {
    float xv = xr[d];
    sq += xv * wq[d * H_];
    sk += xv * wk[d * H_];
  }
  q[i] = sq;
  kk[i] = sk;
}

// ---------------- GEMM: y[n,c] = sum_d x[n,d] Wr[d,c]   (one relation) ----------------
__global__ __launch_bounds__(256) void k_gemm(const float* __restrict__ x,
                                              const float* __restrict__ Wr,
                                              float* __restrict__ y) {
  constexpr int BM = 128, BN = 128, BK = 32, BMP = BM + 1;
  __shared__ float xs[BK][BMP];
  __shared__ float ws[BK][BN];
  const int t = threadIdx.x;
  const int m0 = blockIdx.x * BM;
  const int c0 = blockIdx.y * BN;
  const int tx = t & 15, ty = t >> 4;
  float acc[8][8];
#pragma unroll
  for (int i = 0; i < 8; ++i)
#pragma unroll
    for (int j = 0; j < 8; ++j) acc[i][j] = 0.f;

  for (int k0 = 0; k0 < D_; k0 += BK) {
#pragma unroll
    for (int i = 0; i < 4; ++i) {
      int idx = t + 256 * i;         // 1024 float4s
      int row = idx >> 3;            // 0..127
      int col = (idx & 7) * 4;       // 0..28
      const float4 v = *(const float4*)&x[(size_t)(m0 + row) * D_ + k0 + col];
      xs[col + 0][row] = v.x;
      xs[col + 1][row] = v.y;
      xs[col + 2][row] = v.z;
      xs[col + 3][row] = v.w;
    }
#pragma unroll
    for (int i = 0; i < 4; ++i) {
      int idx = t + 256 * i;
      int row = idx >> 5;            // 0..31
      int col = (idx & 31) * 4;      // 0..124
      *(float4*)&ws[row][col] = *(const float4*)&Wr[(size_t)(k0 + row) * HK_ + c0 + col];
    }
    __syncthreads();
#pragma unroll
    for (int kq = 0; kq < BK; ++kq) {
      float a[8], b[8];
#pragma unroll
      for (int i = 0; i < 8; ++i) a[i] = xs[kq][ty * 8 + i];
      const float4 b0 = *(const float4*)&ws[kq][4 * tx];
      const float4 b1 = *(const float4*)&ws[kq][64 + 4 * tx];
      b[0] = b0.x; b[1] = b0.y; b[2] = b0.z; b[3] = b0.w;
      b[4] = b1.x; b[5] = b1.y; b[6] = b1.z; b[7] = b1.w;
#pragma unroll
      for (int i = 0; i < 8; ++i)
#pragma unroll
        for (int j = 0; j < 8; ++j) acc[i][j] = fmaf(a[i], b[j], acc[i][j]);
    }
    __syncthreads();
  }
#pragma unroll
  for (int i = 0; i < 8; ++i) {
    int n = m0 + ty * 8 + i;
    size_t basep = (size_t)n * HK_ + c0;
    float4 v0 = make_float4(acc[i][0], acc[i][1], acc[i][2], acc[i][3]);
    float4 v1 = make_float4(acc[i][4], acc[i][5], acc[i][6], acc[i][7]);
    *(float4*)&y[basep + 4 * tx] = v0;
    *(float4*)&y[basep + 64 + 4 * tx] = v1;
  }
}

// ---------------- per-edge attention logits (leaky relu) ----------------
__global__ void k_alpha(const int* __restrict__ src, const int* __restrict__ dst,
                        const int* __restrict__ et, const float* __restrict__ q,
                        const float* __restrict__ kk, float* __restrict__ alpha) {
  int i = blockIdx.x * blockDim.x + threadIdx.x; // E*H
  if (i >= E_ * H_) return;
  int h = i & 3, e = i >> 2;
  int r = et[e];
  float v = q[((size_t)dst[e] * R_ + r) * H_ + h] + kk[((size_t)src[e] * R_ + r) * H_ + h];
  alpha[i] = v >= 0.f ? v : 0.2f * v;
}

// ---------------- per-dst softmax stats (max, sum-exp) ----------------
__global__ void k_stats(const int* __restrict__ indptr, const int* __restrict__ esort,
                        const float* __restrict__ alpha, float* __restrict__ nm,
                        float* __restrict__ nd) {
  int i = blockIdx.x * blockDim.x + threadIdx.x; // N*H
  if (i >= N_ * H_) return;
  int h = i & 3, n = i >> 2;
  int b = indptr[n], e2 = indptr[n + 1];
  float m = -3.4e38f;
  for (int j = b; j < e2; ++j) m = fmaxf(m, alpha[esort[j] * H_ + h]);
  float s = 0.f;
  for (int j = b; j < e2; ++j) s += expf(alpha[esort[j] * H_ + h] - m);
  nm[i] = m;
  nd[i] = s;
}

// ---------------- normalize weights; fold in head-mean 0.25 ----------------
__global__ void k_norm(const int* __restrict__ dst, const float* __restrict__ nm,
                       const float* __restrict__ nd, float* __restrict__ alpha) {
  int i = blockIdx.x * blockDim.x + threadIdx.x; // E*H
  if (i >= E_ * H_) return;
  int h = i & 3, e = i >> 2;
  int n = dst[e];
  float a = expf(alpha[i] - nm[n * H_ + h]) / (nd[n * H_ + h] + 1e-16f);
  alpha[i] = a * 0.25f;
}

// ---------------- aggregation for one relation: wave per dst node ----------------
__global__ __launch_bounds__(256) void k_agg(
    const int* __restrict__ indptr, const int* __restrict__ esort,
    const int* __restrict__ src, const int* __restrict__ et,
    const float* __restrict__ a, const float* __restrict__ y,
    float* __restrict__ acc, int r) {
  int n = blockIdx.x * 4 + (threadIdx.x >> 6);
  int lane = threadIdx.x & 63;
  if (n >= N_) return;
  int b = indptr[n], e2 = indptr[n + 1];
  float s0 = 0.f, s1 = 0.f;
  bool any = false;
  for (int j = b; j < e2; ++j) {
    int e = esort[j];
    if (et[e] != r) continue;   // wave-uniform branch (e uniform across wave)
    any = true;
    int s = src[e];
    const float* row = y + (size_t)s * HK_;
    float w0 = a[e * 4 + 0], w1 = a[e * 4 + 1], w2 = a[e * 4 + 2], w3 = a[e * 4 + 3];
    s0 += w0 * row[0 * 128 + lane] + w1 * row[1 * 128 + lane] +
          w2 * row[2 * 128 + lane] + w3 * row[3 * 128 + lane];
    s1 += w0 * row[0 * 128 + 64 + lane] + w1 * row[1 * 128 + 64 + lane] +
          w2 * row[2 * 128 + 64 + lane] + w3 * row[3 * 128 + 64 + lane];
  }
  if (any) {
    acc[(size_t)n * D_ + lane] += s0;
    acc[(size_t)n * D_ + 64 + lane] += s1;
  }
}

// ---------------- bias + relu ----------------
__global__ void k_bias_relu(float* __restrict__ x, const float* __restrict__ Bl) {
  int i = blockIdx.x * blockDim.x + threadIdx.x;
  if (i < N_ * D_) x[i] = fmaxf(x[i] + Bl[i & 127], 0.f);
}

// ---------------- graph mean-pool ----------------
__global__ void k_pool(const float* __restrict__ x, float* __restrict__ pooled) {
  int i = blockIdx.x * blockDim.x + threadIdx.x; // G*D
  if (i >= G_ * D_) return;
  int d = i & 127, g = i >> 7;
  float s = 0.f;
  for (int j = 0; j < NPG_; ++j) s += x[(size_t)(g * NPG_ + j) * D_ + d];
  pooled[i] = s * (1.0f / NPG_);
}

// ---------------- head MLP: fc1 + policy + value ----------------
__global__ void k_head(const float* __restrict__ pooled, const float* __restrict__ fc1w,
                       const float* __restrict__ fc1b, const float* __restrict__ polw,
                       const float* __restrict__ polb, const float* __restrict__ valw,
                       const float* __restrict__ valb, float* __restrict__ out) {
  int g = blockIdx.x;
  int t = threadIdx.x; // 64
  __shared__ float hb[64];
  const float* p = pooled + (size_t)g * D_;
  float s = fc1b[t];
  for (int d = 0; d < D_; ++d) s += p[d] * fc1w[d * 64 + t];
  hb[t] = fmaxf(s, 0.f);
  __syncthreads();
  if (t < 7) {
    float s2 = polb[t];
    for (int j = 0; j < 64; ++j) s2 += hb[j] * polw[j * 7 + t];
    out[g * 7 + t] = s2;
  } else if (t == 7) {
    float s2 = valb[0];
    for (int j = 0; j < 64; ++j) s2 += hb[j] * valw[j];
    out[G_ * 7 + g] = tanhf(s2);
  }
}

extern "C" void kernel_launch(void* const* d_in, const int* in_sizes, int n_in,
                              void* d_out, int out_size, void* d_ws, size_t ws_size,
                              hipStream_t stream) {
  (void)in_sizes; (void)n_in; (void)out_size;
  const int*   x_nodes = (const int*)d_in[0];
  const int*   eidx    = (const int*)d_in[1];
  const int*   etype   = (const int*)d_in[2];
  const float* emb     = (const float*)d_in[4];
  const float* W       = (const float*)d_in[5];
  const float* Q       = (const float*)d_in[6];
  const float* Km      = (const float*)d_in[7];
  const float* B       = (const float*)d_in[8];
  const float* fc1w    = (const float*)d_in[9];
  const float* fc1b    = (const float*)d_in[10];
  const float* polw    = (const float*)d_in[11];
  const float* polb    = (const float*)d_in[12];
  const float* valw    = (const float*)d_in[13];
  const float* valb    = (const float*)d_in[14];
  float* out = (float*)d_out;
  const int* srcA = eidx;        // edge_index[0,:]
  const int* dstA = eidx + E_;   // edge_index[1,:]

  char* p = (char*)d_ws;
  size_t used = 0;
  auto carve = [&](size_t bytes) {
    char* q = p;
    size_t adv = (bytes + 255) & ~(size_t)255;
    p += adv;
    used += adv;
    return q;
  };
  float* x_cur  = (float*)carve((size_t)N_ * D_ * 4);        // 10.5 MB
  float* x_nxt  = (float*)carve((size_t)N_ * D_ * 4);        // 10.5 MB
  float* ybuf   = (float*)carve((size_t)N_ * HK_ * 4);       // 41.9 MB
  float* qbuf   = (float*)carve((size_t)N_ * R_ * H_ * 4);   // 2.6 MB
  float* kbuf   = (float*)carve((size_t)N_ * R_ * H_ * 4);   // 2.6 MB
  float* albuf  = (float*)carve((size_t)E_ * H_ * 4);        // 2.6 MB
  float* nmb    = (float*)carve((size_t)N_ * H_ * 4);
  float* ndb    = (float*)carve((size_t)N_ * H_ * 4);
  float* WQb    = (float*)carve((size_t)R_ * D_ * H_ * 4);
  float* WKb    = (float*)carve((size_t)R_ * D_ * H_ * 4);
  float* pooled = (float*)carve((size_t)G_ * D_ * 4);
  int* counts   = (int*)carve((size_t)N_ * 4);
  int* indptr   = (int*)carve((size_t)(N_ + 1) * 4);
  int* cursor   = (int*)carve((size_t)N_ * 4);
  int* esort    = (int*)carve((size_t)E_ * 4);
  if (used > ws_size) return;  // defensive: fail loudly (poison output) instead of OOB crash

  k_zero_i<<<(N_ + 255) / 256, 256, 0, stream>>>(counts, N_);
  k_count<<<E_ / 256, 256, 0, stream>>>(dstA, counts);
  k_scan<<<1, 256, 0, stream>>>(counts, indptr, cursor);
  k_scatter<<<E_ / 256, 256, 0, stream>>>(dstA, cursor, esort);
  k_embed<<<(N_ * D_) / 256, 256, 0, stream>>>(x_nodes, emb, x_cur);

  for (int l = 0; l < L_; ++l) {
    const float* Wl = W + (size_t)l * R_ * D_ * HK_;
    const float* Ql = Q + (size_t)l * HK_ * H_;
    const float* Kl = Km + (size_t)l * HK_ * H_;
    const float* Bl = B + (size_t)l * D_;
    k_wqk<<<(R_ * D_ * H_) / 256, 256, 0, stream>>>(Wl, Ql, Kl, WQb, WKb);
    k_qk<<<(N_ * R_ * H_) / 256, 256, 0, stream>>>(x_cur, WQb, WKb, qbuf, kbuf);
    k_alpha<<<(E_ * H_) / 256, 256, 0, stream>>>(srcA, dstA, etype, qbuf, kbuf, albuf);
    k_stats<<<(N_ * H_) / 256, 256, 0, stream>>>(indptr, esort, albuf, nmb, ndb);
    k_norm<<<(E_ * H_) / 256, 256, 0, stream>>>(dstA, nmb, ndb, albuf);
    k_zero_f<<<(N_ * D_) / 256, 256, 0, stream>>>(x_nxt, N_ * D_);
    for (int r = 0; r < R_; ++r) {
      const float* Wr = Wl + (size_t)r * D_ * HK_;
      k_gemm<<<dim3(N_ / 128, HK_ / 128), 256, 0, stream>>>(x_cur, Wr, ybuf);
      k_agg<<<N_ / 4, 256, 0, stream>>>(indptr, esort, srcA, etype, albuf, ybuf,
                                        x_nxt, r);
    }
    k_bias_relu<<<(N_ * D_) / 256, 256, 0, stream>>>(x_nxt, Bl);
    float* tmp = x_cur; x_cur = x_nxt; x_nxt = tmp;
  }

  k_pool<<<(G_ * D_) / 256, 256, 0, stream>>>(x_cur, pooled);
  k_head<<<G_, 64, 0, stream>>>(pooled, fc1w, fc1b, polw, polb, valw, valb, out);
}

// Round 3
// 1587.428 us; speedup vs baseline: 1.9658x; 1.9658x over previous
//
#include <hip/hip_runtime.h>
#include <cstdint>
#include <cstddef>

constexpr int N_  = 20480;
constexpr int E_  = 163840;
constexpr int G_  = 512;
constexpr int D_  = 128;
constexpr int H_  = 4;
constexpr int R_  = 8;
constexpr int L_  = 4;
constexpr int HK_ = 512;   // H*D
constexpr int NPG_ = N_ / G_; // 40

typedef short short8 __attribute__((ext_vector_type(8)));
typedef float f32x4 __attribute__((ext_vector_type(4)));
typedef unsigned short u16;

__device__ inline u16 bfr(float f) {  // fp32 -> bf16 RNE (no NaN handling needed)
  unsigned u = __builtin_bit_cast(unsigned, f);
  return (u16)((u + 0x7fffu + ((u >> 16) & 1u)) >> 16);
}

// ---------------- zero helpers ----------------
__global__ void k_zero_i(int* __restrict__ p, int n) {
  int i = blockIdx.x * blockDim.x + threadIdx.x;
  if (i < n) p[i] = 0;
}
__global__ void k_zero_f(float* __restrict__ p, int n) {
  int i = blockIdx.x * blockDim.x + threadIdx.x;
  if (i < n) p[i] = 0.f;
}

// ---------------- CSR builds ----------------
__global__ void k_count_dst(const int* __restrict__ dst, int* __restrict__ counts) {
  int e = blockIdx.x * blockDim.x + threadIdx.x;
  if (e < E_) atomicAdd(&counts[dst[e]], 1);
}
__global__ void k_count_rel(const int* __restrict__ dst, const int* __restrict__ et,
                            int* __restrict__ counts) {
  int e = blockIdx.x * blockDim.x + threadIdx.x;
  if (e < E_) atomicAdd(&counts[et[e] * N_ + dst[e]], 1);
}
// generic exclusive scan over `total` entries (total % 256 == 0), single block
__global__ void k_scan(const int* __restrict__ counts, int* __restrict__ indptr,
                       int* __restrict__ cursor, int total) {
  __shared__ int part[256];
  __shared__ int offs[257];
  int t = threadIdx.x;
  const int per = total / 256;
  int base = t * per;
  int s = 0;
  for (int i = 0; i < per; ++i) s += counts[base + i];
  part[t] = s;
  __syncthreads();
  if (t == 0) {
    offs[0] = 0;
    for (int i = 0; i < 256; ++i) offs[i + 1] = offs[i] + part[i];
  }
  __syncthreads();
  int run = offs[t];
  for (int i = 0; i < per; ++i) {
    indptr[base + i] = run;
    cursor[base + i] = run;
    run += counts[base + i];
  }
  if (t == 255) indptr[total] = run;
}
__global__ void k_scatter_dst(const int* __restrict__ dst, int* __restrict__ cursor,
                              int* __restrict__ esort) {
  int e = blockIdx.x * blockDim.x + threadIdx.x;
  if (e < E_) {
    int p = atomicAdd(&cursor[dst[e]], 1);
    esort[p] = e;
  }
}
__global__ void k_scatter_rel(const int* __restrict__ dst, const int* __restrict__ et,
                              int* __restrict__ cursor, int* __restrict__ esort) {
  int e = blockIdx.x * blockDim.x + threadIdx.x;
  if (e < E_) {
    int p = atomicAdd(&cursor[et[e] * N_ + dst[e]], 1);
    esort[p] = e;
  }
}

// ---------------- embedding lookup ----------------
__global__ void k_embed(const int* __restrict__ xn, const float* __restrict__ emb,
                        float* __restrict__ x) {
  int i = blockIdx.x * blockDim.x + threadIdx.x;
  if (i < N_ * D_) {
    int n = i >> 7, d = i & 127;
    x[i] = emb[xn[n] * D_ + d];
  }
}

// ---------------- WQK[d][c]: c<32 -> W[r,d,:]@Q[:,h]; c>=32 -> @K (r=(c&31)>>2,h=c&3) ----------------
__global__ void k_wqk(const float* __restrict__ Wl, const float* __restrict__ Ql,
                      const float* __restrict__ Kl, float* __restrict__ WQK) {
  int i = blockIdx.x * blockDim.x + threadIdx.x; // D*64 = 8192
  if (i >= D_ * 64) return;
  int c = i & 63, d = i >> 6;
  int r = (c & 31) >> 2, h = c & 3;
  const float* wrow = Wl + ((size_t)r * D_ + d) * HK_;
  const float* m = (c < 32) ? Ql : Kl;
  float s = 0.f;
  for (int k = 0; k < HK_; ++k) s += wrow[k] * m[k * H_ + h];
  WQK[d * 64 + c] = s;
}

// ---------------- q,k: LDS-tiled small GEMM (32 nodes/block) ----------------
__global__ __launch_bounds__(256) void k_qk(const float* __restrict__ x,
                                            const float* __restrict__ WQK,
                                            float* __restrict__ q,
                                            float* __restrict__ kk) {
  __shared__ float xs[32][129];
  __shared__ float wq[128][64];
  const int t = threadIdx.x;
  const int n0 = blockIdx.x * 32;
#pragma unroll
  for (int p = 0; p < 4; ++p) {      // 1024 float4 of x
    int idx = t + p * 256;
    int row = idx >> 5, c4 = (idx & 31) * 4;
    const float4 v = *(const float4*)&x[(size_t)(n0 + row) * D_ + c4];
    xs[row][c4 + 0] = v.x; xs[row][c4 + 1] = v.y;
    xs[row][c4 + 2] = v.z; xs[row][c4 + 3] = v.w;
  }
#pragma unroll
  for (int p = 0; p < 8; ++p) {      // 2048 float4 of WQK
    int idx = t + p * 256;
    int row = idx >> 4, c4 = (idx & 15) * 4;
    *(float4*)&wq[row][c4] = *(const float4*)&WQK[row * 64 + c4];
  }
  __syncthreads();
  const int node = t >> 3, cq = t & 7;   // 8 outputs per thread
  float s[8];
#pragma unroll
  for (int j = 0; j < 8; ++j) s[j] = 0.f;
  for (int k = 0; k < 128; ++k) {
    float xv = xs[node][k];
#pragma unroll
    for (int j = 0; j < 8; ++j) s[j] = fmaf(xv, wq[k][cq * 8 + j], s[j]);
  }
#pragma unroll
  for (int j = 0; j < 8; ++j) {
    int c = cq * 8 + j;
    if (c < 32) q[(size_t)(n0 + node) * 32 + c] = s[j];
    else        kk[(size_t)(n0 + node) * 32 + (c - 32)] = s[j];
  }
}

// ---------------- per-edge attention logits (leaky relu) ----------------
__global__ void k_alpha(const int* __restrict__ src, const int* __restrict__ dst,
                        const int* __restrict__ et, const float* __restrict__ q,
                        const float* __restrict__ kk, float* __restrict__ alpha) {
  int i = blockIdx.x * blockDim.x + threadIdx.x; // E*H
  if (i >= E_ * H_) return;
  int h = i & 3, e = i >> 2;
  int r = et[e];
  float v = q[(size_t)dst[e] * 32 + r * 4 + h] + kk[(size_t)src[e] * 32 + r * 4 + h];
  alpha[i] = v >= 0.f ? v : 0.2f * v;
}

// ---------------- per-dst softmax stats (max, sum-exp) over dst-CSR ----------------
__global__ void k_stats(const int* __restrict__ indptr, const int* __restrict__ esort,
                        const float* __restrict__ alpha, float* __restrict__ nm,
                        float* __restrict__ nd) {
  int i = blockIdx.x * blockDim.x + threadIdx.x; // N*H
  if (i >= N_ * H_) return;
  int h = i & 3, n = i >> 2;
  int b = indptr[n], e2 = indptr[n + 1];
  float m = -3.4e38f;
  for (int j = b; j < e2; ++j) m = fmaxf(m, alpha[esort[j] * H_ + h]);
  float s = 0.f;
  for (int j = b; j < e2; ++j) s += expf(alpha[esort[j] * H_ + h] - m);
  nm[i] = m;
  nd[i] = s;
}

// ---------------- normalize weights; fold in head-mean 0.25 ----------------
__global__ void k_norm(const int* __restrict__ dst, const float* __restrict__ nm,
                       const float* __restrict__ nd, float* __restrict__ alpha) {
  int i = blockIdx.x * blockDim.x + threadIdx.x; // E*H
  if (i >= E_ * H_) return;
  int h = i & 3, e = i >> 2;
  int n = dst[e];
  float a = expf(alpha[i] - nm[n * H_ + h]) / (nd[n * H_ + h] + 1e-16f);
  alpha[i] = a * 0.25f;
}

// ---------------- fp32 -> bf16 conversions ----------------
__global__ void k_cvt_x(const float* __restrict__ x, u16* __restrict__ xb) {
  int i = blockIdx.x * blockDim.x + threadIdx.x; // N*D/4
  if (i >= N_ * D_ / 4) return;
  const float4 v = ((const float4*)x)[i];
  uint2 o;
  o.x = (unsigned)bfr(v.x) | ((unsigned)bfr(v.y) << 16);
  o.y = (unsigned)bfr(v.z) | ((unsigned)bfr(v.w) << 16);
  *(uint2*)&xb[(size_t)i * 4] = o;
}

// W[l] fp32 [R][D][HK] -> wt bf16 [R][HK][D]  (transpose via LDS tile)
__global__ void k_cvt_w(const float* __restrict__ Wl, u16* __restrict__ wt) {
  __shared__ u16 tile[64][65];
  const int r = blockIdx.z, k0 = blockIdx.y * 64, c0 = blockIdx.x * 64;
  const int t = threadIdx.x;
  const int tk = t >> 4, tc4 = (t & 15) * 4;
#pragma unroll
  for (int p = 0; p < 4; ++p) {
    int krow = tk + p * 16;
    const float4 v = *(const float4*)&Wl[((size_t)r * D_ + k0 + krow) * HK_ + c0 + tc4];
    tile[tc4 + 0][krow] = bfr(v.x);
    tile[tc4 + 1][krow] = bfr(v.y);
    tile[tc4 + 2][krow] = bfr(v.z);
    tile[tc4 + 3][krow] = bfr(v.w);
  }
  __syncthreads();
#pragma unroll
  for (int p = 0; p < 4; ++p) {
    int crow = tk + p * 16;
    uint2 o;
    o.x = (unsigned)tile[crow][tc4 + 0] | ((unsigned)tile[crow][tc4 + 1] << 16);
    o.y = (unsigned)tile[crow][tc4 + 2] | ((unsigned)tile[crow][tc4 + 3] << 16);
    *(uint2*)&wt[((size_t)r * HK_ + c0 + crow) * D_ + k0 + tc4] = o;
  }
}

// ---------------- MFMA GEMM: y[128 x 128 tile] = xb[m,k] * wt_r[c,k]^T ----------------
// xb: [N][128] bf16, wt_r: [512][128] bf16 (N-major), y: [N][512] fp32
__global__ __launch_bounds__(256) void k_mfma(const u16* __restrict__ xb,
                                              const u16* __restrict__ wt,
                                              float* __restrict__ y) {
  __shared__ unsigned char lds[65536];  // A: 0..32KB, B: 32..64KB, both [128 rows][256B]
  const int t = threadIdx.x;
  const int m0 = blockIdx.x * 128;
  const int c0 = blockIdx.y * 128;
#pragma unroll
  for (int p = 0; p < 8; ++p) {
    int idx = t + p * 256;
    int row = idx >> 4, seg = idx & 15;
    int lb = row * 256 + ((seg * 16) ^ ((row & 7) << 4));  // XOR swizzle (G4)
    uint4 va = *(const uint4*)(xb + (size_t)(m0 + row) * 128 + seg * 8);
    *(uint4*)(lds + lb) = va;
    uint4 vb = *(const uint4*)(wt + (size_t)(c0 + row) * 128 + seg * 8);
    *(uint4*)(lds + 32768 + lb) = vb;
  }
  __syncthreads();
  const int wid = t >> 6, lane = t & 63;
  const int wr = (wid >> 1) * 64, wc = (wid & 1) * 64;
  const int l15 = lane & 15, l4 = lane >> 4;
  f32x4 acc[4][4];
#pragma unroll
  for (int i = 0; i < 4; ++i)
#pragma unroll
    for (int j = 0; j < 4; ++j) acc[i][j] = (f32x4){0.f, 0.f, 0.f, 0.f};
#pragma unroll
  for (int ks = 0; ks < 4; ++ks) {
    short8 a[4], b[4];
#pragma unroll
    for (int i = 0; i < 4; ++i) {
      int row = wr + i * 16 + l15;
      int ko = (l4 * 16 + ks * 64) ^ ((row & 7) << 4);
      a[i] = *(const short8*)(lds + row * 256 + ko);
      int col = wc + i * 16 + l15;
      int ko2 = (l4 * 16 + ks * 64) ^ ((col & 7) << 4);
      b[i] = *(const short8*)(lds + 32768 + col * 256 + ko2);
    }
#pragma unroll
    for (int i = 0; i < 4; ++i)
#pragma unroll
      for (int j = 0; j < 4; ++j)
        acc[i][j] = __builtin_amdgcn_mfma_f32_16x16x32_bf16(a[i], b[j], acc[i][j], 0, 0, 0);
  }
  // C/D layout: col = lane&15, row = (lane>>4)*4 + reg   [m89/m91]
#pragma unroll
  for (int i = 0; i < 4; ++i) {
    int rowb = m0 + wr + i * 16 + l4 * 4;
#pragma unroll
    for (int j = 0; j < 4; ++j) {
      int col = c0 + wc + j * 16 + l15;
#pragma unroll
      for (int rg = 0; rg < 4; ++rg)
        y[(size_t)(rowb + rg) * HK_ + col] = acc[i][j][rg];
    }
  }
}

// ---------------- aggregation over one relation's CSR slice; wave per dst ----------------
__global__ __launch_bounds__(256) void k_agg(
    const int* __restrict__ ip, const int* __restrict__ es,
    const int* __restrict__ src, const float* __restrict__ a,
    const float* __restrict__ y, float* __restrict__ acc) {
  int n = blockIdx.x * 4 + (threadIdx.x >> 6);
  int lane = threadIdx.x & 63;
  int b = ip[n], e2 = ip[n + 1];
  if (b >= e2) return;
  float s0 = 0.f, s1 = 0.f;
  for (int j = b; j < e2; ++j) {
    int e = es[j];
    int s = src[e];
    const float* row = y + (size_t)s * HK_;
    float w0 = a[e * 4 + 0], w1 = a[e * 4 + 1], w2 = a[e * 4 + 2], w3 = a[e * 4 + 3];
    s0 += w0 * row[lane]       + w1 * row[128 + lane] +
          w2 * row[256 + lane] + w3 * row[384 + lane];
    s1 += w0 * row[64 + lane]  + w1 * row[192 + lane] +
          w2 * row[320 + lane] + w3 * row[448 + lane];
  }
  acc[(size_t)n * D_ + lane] += s0;
  acc[(size_t)n * D_ + 64 + lane] += s1;
}

// ---------------- bias + relu ----------------
__global__ void k_bias_relu(float* __restrict__ x, const float* __restrict__ Bl) {
  int i = blockIdx.x * blockDim.x + threadIdx.x;
  if (i < N_ * D_) x[i] = fmaxf(x[i] + Bl[i & 127], 0.f);
}

// ---------------- graph mean-pool ----------------
__global__ void k_pool(const float* __restrict__ x, float* __restrict__ pooled) {
  int i = blockIdx.x * blockDim.x + threadIdx.x; // G*D
  if (i >= G_ * D_) return;
  int d = i & 127, g = i >> 7;
  float s = 0.f;
  for (int j = 0; j < NPG_; ++j) s += x[(size_t)(g * NPG_ + j) * D_ + d];
  pooled[i] = s * (1.0f / NPG_);
}

// ---------------- head MLP ----------------
__global__ void k_head(const float* __restrict__ pooled, const float* __restrict__ fc1w,
                       const float* __restrict__ fc1b, const float* __restrict__ polw,
                       const float* __restrict__ polb, const float* __restrict__ valw,
                       const float* __restrict__ valb, float* __restrict__ out) {
  int g = blockIdx.x;
  int t = threadIdx.x; // 64
  __shared__ float hb[64];
  const float* p = pooled + (size_t)g * D_;
  float s = fc1b[t];
  for (int d = 0; d < D_; ++d) s += p[d] * fc1w[d * 64 + t];
  hb[t] = fmaxf(s, 0.f);
  __syncthreads();
  if (t < 7) {
    float s2 = polb[t];
    for (int j = 0; j < 64; ++j) s2 += hb[j] * polw[j * 7 + t];
    out[g * 7 + t] = s2;
  } else if (t == 7) {
    float s2 = valb[0];
    for (int j = 0; j < 64; ++j) s2 += hb[j] * valw[j];
    out[G_ * 7 + g] = tanhf(s2);
  }
}

extern "C" void kernel_launch(void* const* d_in, const int* in_sizes, int n_in,
                              void* d_out, int out_size, void* d_ws, size_t ws_size,
                              hipStream_t stream) {
  (void)in_sizes; (void)n_in; (void)out_size;
  const int*   x_nodes = (const int*)d_in[0];
  const int*   eidx    = (const int*)d_in[1];
  const int*   etype   = (const int*)d_in[2];
  const float* emb     = (const float*)d_in[4];
  const float* W       = (const float*)d_in[5];
  const float* Q       = (const float*)d_in[6];
  const float* Km      = (const float*)d_in[7];
  const float* B       = (const float*)d_in[8];
  const float* fc1w    = (const float*)d_in[9];
  const float* fc1b    = (const float*)d_in[10];
  const float* polw    = (const float*)d_in[11];
  const float* polb    = (const float*)d_in[12];
  const float* valw    = (const float*)d_in[13];
  const float* valb    = (const float*)d_in[14];
  float* out = (float*)d_out;
  const int* srcA = eidx;        // edge_index[0,:]
  const int* dstA = eidx + E_;   // edge_index[1,:]

  char* p = (char*)d_ws;
  size_t used = 0;
  auto carve = [&](size_t bytes) {
    char* q = p;
    size_t adv = (bytes + 255) & ~(size_t)255;
    p += adv;
    used += adv;
    return q;
  };
  float* x_cur  = (float*)carve((size_t)N_ * D_ * 4);        // 10.5 MB
  float* x_nxt  = (float*)carve((size_t)N_ * D_ * 4);        // 10.5 MB
  float* ybuf   = (float*)carve((size_t)N_ * HK_ * 4);       // 41.9 MB
  float* qk_reg = (float*)carve((size_t)N_ * 64 * 4);        // 5.24 MB (q,k; aliased by xbf)
  float* qbuf   = qk_reg;                                     // [N][32]
  float* kbuf   = qk_reg + (size_t)N_ * 32;                   // [N][32]
  u16*   xbf    = (u16*)qk_reg;                               // alias: [N][128] bf16 (q/k dead by then)
  float* albuf  = (float*)carve((size_t)E_ * H_ * 4);        // 2.6 MB
  float* nmb    = (float*)carve((size_t)N_ * H_ * 4);
  float* ndb    = (float*)carve((size_t)N_ * H_ * 4);
  float* WQKb   = (float*)carve((size_t)D_ * 64 * 4);
  u16*   Wtb    = (u16*)carve((size_t)R_ * HK_ * D_ * 2);    // 1.05 MB
  float* pooled = (float*)carve((size_t)G_ * D_ * 4);
  int* countsN  = (int*)carve((size_t)N_ * 4);
  int* cursorD  = (int*)carve((size_t)N_ * 4);
  int* indptrD  = (int*)carve((size_t)(N_ + 1) * 4);
  int* esortD   = (int*)carve((size_t)E_ * 4);
  int* countsR  = (int*)carve((size_t)R_ * N_ * 4);
  int* cursorR  = (int*)carve((size_t)R_ * N_ * 4);
  int* indptrR  = (int*)carve((size_t)(R_ * N_ + 1) * 4);
  int* esortR   = (int*)carve((size_t)E_ * 4);
  if (used > ws_size) return;  // defensive: fail via poisoned output, not OOB crash

  // ---- CSR builds (static graph, rebuilt each call for determinism) ----
  k_zero_i<<<(N_ + 255) / 256, 256, 0, stream>>>(countsN, N_);
  k_zero_i<<<(R_ * N_ + 255) / 256, 256, 0, stream>>>(countsR, R_ * N_);
  k_count_dst<<<E_ / 256, 256, 0, stream>>>(dstA, countsN);
  k_count_rel<<<E_ / 256, 256, 0, stream>>>(dstA, etype, countsR);
  k_scan<<<1, 256, 0, stream>>>(countsN, indptrD, cursorD, N_);
  k_scan<<<1, 256, 0, stream>>>(countsR, indptrR, cursorR, R_ * N_);
  k_scatter_dst<<<E_ / 256, 256, 0, stream>>>(dstA, cursorD, esortD);
  k_scatter_rel<<<E_ / 256, 256, 0, stream>>>(dstA, etype, cursorR, esortR);
  k_embed<<<(N_ * D_) / 256, 256, 0, stream>>>(x_nodes, emb, x_cur);

  for (int l = 0; l < L_; ++l) {
    const float* Wl = W + (size_t)l * R_ * D_ * HK_;
    const float* Ql = Q + (size_t)l * HK_ * H_;
    const float* Kl = Km + (size_t)l * HK_ * H_;
    const float* Bl = B + (size_t)l * D_;
    // attention path (fp32)
    k_wqk<<<(D_ * 64) / 256, 256, 0, stream>>>(Wl, Ql, Kl, WQKb);
    k_qk<<<N_ / 32, 256, 0, stream>>>(x_cur, WQKb, qbuf, kbuf);
    k_alpha<<<(E_ * H_) / 256, 256, 0, stream>>>(srcA, dstA, etype, qbuf, kbuf, albuf);
    k_stats<<<(N_ * H_) / 256, 256, 0, stream>>>(indptrD, esortD, albuf, nmb, ndb);
    k_norm<<<(E_ * H_) / 256, 256, 0, stream>>>(dstA, nmb, ndb, albuf);
    // transform + aggregate (bf16 MFMA; xbf aliases q/k which are dead now)
    k_cvt_x<<<(N_ * D_ / 4) / 256, 256, 0, stream>>>(x_cur, xbf);
    k_cvt_w<<<dim3(HK_ / 64, D_ / 64, R_), 256, 0, stream>>>(Wl, Wtb);
    k_zero_f<<<(N_ * D_) / 256, 256, 0, stream>>>(x_nxt, N_ * D_);
    for (int r = 0; r < R_; ++r) {
      k_mfma<<<dim3(N_ / 128, HK_ / 128), 256, 0, stream>>>(
          xbf, Wtb + (size_t)r * HK_ * D_, ybuf);
      k_agg<<<N_ / 4, 256, 0, stream>>>(indptrR + (size_t)r * N_, esortR, srcA,
                                        albuf, ybuf, x_nxt);
    }
    k_bias_relu<<<(N_ * D_) / 256, 256, 0, stream>>>(x_nxt, Bl);
    float* tmp = x_cur; x_cur = x_nxt; x_nxt = tmp;
  }

  k_pool<<<(G_ * D_) / 256, 256, 0, stream>>>(x_cur, pooled);
  k_head<<<G_, 64, 0, stream>>>(pooled, fc1w, fc1b, polw, polb, valw, valb, out);
}

// Round 4
// 1107.213 us; speedup vs baseline: 2.8184x; 1.4337x over previous
//
#include <hip/hip_runtime.h>
#include <cstdint>
#include <cstddef>

constexpr int N_  = 20480;
constexpr int E_  = 163840;
constexpr int G_  = 512;
constexpr int D_  = 128;
constexpr int H_  = 4;
constexpr int R_  = 8;
constexpr int L_  = 4;
constexpr int HK_ = 512;   // H*D
constexpr int NPG_ = N_ / G_; // 40

typedef short short8 __attribute__((ext_vector_type(8)));
typedef float f32x4 __attribute__((ext_vector_type(4)));
typedef unsigned short u16;
typedef unsigned int u32;

__device__ inline u16 bfr(float f) {  // fp32 -> bf16 RNE
  u32 u = __builtin_bit_cast(u32, f);
  return (u16)((u + 0x7fffu + ((u >> 16) & 1u)) >> 16);
}
__device__ inline float bf2f(u32 lo16) { return __builtin_bit_cast(float, lo16 << 16); }
// order-preserving float<->uint encode for atomicMax
__device__ inline u32 fenc(float f) {
  u32 u = __builtin_bit_cast(u32, f);
  return (u & 0x80000000u) ? ~u : (u | 0x80000000u);
}
__device__ inline float fdec(u32 k) {
  u32 u = (k & 0x80000000u) ? (k ^ 0x80000000u) : ~k;
  return __builtin_bit_cast(float, u);
}

// ---------------- zero helpers ----------------
__global__ void k_zero_i(int* __restrict__ p, int n) {
  int i = blockIdx.x * blockDim.x + threadIdx.x;
  if (i < n) p[i] = 0;
}
__global__ void k_zero_f(float* __restrict__ p, int n) {
  int i = blockIdx.x * blockDim.x + threadIdx.x;
  if (i < n) p[i] = 0.f;
}
__global__ void k_zero_nmnd(u32* __restrict__ nm, float* __restrict__ nd, int n) {
  int i = blockIdx.x * blockDim.x + threadIdx.x;
  if (i < n) { nm[i] = 0u; nd[i] = 0.f; }   // enc 0 == "-inf" sentinel
}

// ---------------- rel-CSR build (edges keyed by r*N+dst) ----------------
__global__ void k_count_rel(const int* __restrict__ dst, const int* __restrict__ et,
                            int* __restrict__ counts) {
  int e = blockIdx.x * blockDim.x + threadIdx.x;
  if (e < E_) atomicAdd(&counts[et[e] * N_ + dst[e]], 1);
}
// phase 1: per-block (1024 items) sums
__global__ void k_bsum(const int* __restrict__ c, int* __restrict__ bsum) {
  int t = threadIdx.x;
  const int4 v = *(const int4*)&c[blockIdx.x * 1024 + t * 4];
  int s = v.x + v.y + v.z + v.w;
#pragma unroll
  for (int o = 32; o; o >>= 1) s += __shfl_down(s, o, 64);
  __shared__ int ws_[4];
  if ((t & 63) == 0) ws_[t >> 6] = s;
  __syncthreads();
  if (t == 0) bsum[blockIdx.x] = ws_[0] + ws_[1] + ws_[2] + ws_[3];
}
// phase 2: exclusive scan of nb (<=512) block sums, single block
__global__ void k_bscan(int* __restrict__ bsum, int nb, int* __restrict__ tot_out) {
  __shared__ int sh[512];
  int t = threadIdx.x;
  if (t < nb) sh[t] = bsum[t];
  __syncthreads();
  if (t == 0) {
    int run = 0;
    for (int i = 0; i < nb; ++i) { int v = sh[i]; sh[i] = run; run += v; }
    tot_out[0] = run;
  }
  __syncthreads();
  if (t < nb) bsum[t] = sh[t];
}
// phase 3: full exclusive scan write (indptr + cursor)
__global__ void k_scan3(const int* __restrict__ c, const int* __restrict__ bsum,
                        int* __restrict__ indptr, int* __restrict__ cursor) {
  __shared__ int ts[256];
  int t = threadIdx.x;
  int base = blockIdx.x * 1024 + t * 4;
  const int4 v = *(const int4*)&c[base];
  int s0 = v.x, s01 = v.x + v.y, s012 = s01 + v.z, s = s012 + v.w;
  ts[t] = s;
  __syncthreads();
#pragma unroll
  for (int o = 1; o < 256; o <<= 1) {
    int add = (t >= o) ? ts[t - o] : 0;
    __syncthreads();
    ts[t] += add;
    __syncthreads();
  }
  int off = bsum[blockIdx.x] + (t ? ts[t - 1] : 0);
  int4 o4 = make_int4(off, off + s0, off + s01, off + s012);
  *(int4*)&indptr[base] = o4;
  *(int4*)&cursor[base] = o4;
}
__global__ void k_scatter_rel(const int* __restrict__ dst, const int* __restrict__ et,
                              int* __restrict__ cursor, int* __restrict__ esort) {
  int e = blockIdx.x * blockDim.x + threadIdx.x;
  if (e < E_) {
    int p = atomicAdd(&cursor[et[e] * N_ + dst[e]], 1);
    esort[p] = e;
  }
}

// ---------------- embedding lookup ----------------
__global__ void k_embed(const int* __restrict__ xn, const float* __restrict__ emb,
                        float* __restrict__ x) {
  int i = blockIdx.x * blockDim.x + threadIdx.x;
  if (i < N_ * D_) {
    int n = i >> 7, d = i & 127;
    x[i] = emb[xn[n] * D_ + d];
  }
}

// ---------------- WQK[d][c]: c<32 -> W[r,d,:]@Q[:,h]; c>=32 -> @K ----------------
__global__ void k_wqk(const float* __restrict__ Wl, const float* __restrict__ Ql,
                      const float* __restrict__ Kl, float* __restrict__ WQK) {
  int i = blockIdx.x * blockDim.x + threadIdx.x; // D*64 = 8192
  if (i >= D_ * 64) return;
  int c = i & 63, d = i >> 6;
  int r = (c & 31) >> 2, h = c & 3;
  const float4* wrow = (const float4*)(Wl + ((size_t)r * D_ + d) * HK_);
  const float* m = (c < 32) ? Ql : Kl;
  float s = 0.f;
  for (int k4 = 0; k4 < HK_ / 4; ++k4) {
    const float4 w = wrow[k4];
    int k = k4 * 4;
    s += w.x * m[k * H_ + h] + w.y * m[(k + 1) * H_ + h] +
         w.z * m[(k + 2) * H_ + h] + w.w * m[(k + 3) * H_ + h];
  }
  WQK[d * 64 + c] = s;
}

// ---------------- q,k: LDS-tiled small GEMM (32 nodes/block) ----------------
__global__ __launch_bounds__(256) void k_qk(const float* __restrict__ x,
                                            const float* __restrict__ WQK,
                                            float* __restrict__ q,
                                            float* __restrict__ kk) {
  __shared__ float xs[32][129];
  __shared__ float wq[128][64];
  const int t = threadIdx.x;
  const int n0 = blockIdx.x * 32;
#pragma unroll
  for (int p = 0; p < 4; ++p) {
    int idx = t + p * 256;
    int row = idx >> 5, c4 = (idx & 31) * 4;
    const float4 v = *(const float4*)&x[(size_t)(n0 + row) * D_ + c4];
    xs[row][c4 + 0] = v.x; xs[row][c4 + 1] = v.y;
    xs[row][c4 + 2] = v.z; xs[row][c4 + 3] = v.w;
  }
#pragma unroll
  for (int p = 0; p < 8; ++p) {
    int idx = t + p * 256;
    int row = idx >> 4, c4 = (idx & 15) * 4;
    *(float4*)&wq[row][c4] = *(const float4*)&WQK[row * 64 + c4];
  }
  __syncthreads();
  const int node = t >> 3, cq = t & 7;
  float s[8];
#pragma unroll
  for (int j = 0; j < 8; ++j) s[j] = 0.f;
  for (int k = 0; k < 128; ++k) {
    float xv = xs[node][k];
#pragma unroll
    for (int j = 0; j < 8; ++j) s[j] = fmaf(xv, wq[k][cq * 8 + j], s[j]);
  }
#pragma unroll
  for (int j = 0; j < 8; ++j) {
    int c = cq * 8 + j;
    if (c < 32) q[(size_t)(n0 + node) * 32 + c] = s[j];
    else        kk[(size_t)(n0 + node) * 32 + (c - 32)] = s[j];
  }
}

// ---------------- per-edge logits + atomic max ----------------
__global__ void k_alpha_max(const int* __restrict__ src, const int* __restrict__ dst,
                            const int* __restrict__ et, const float* __restrict__ q,
                            const float* __restrict__ kk, float* __restrict__ alpha,
                            u32* __restrict__ nm) {
  int i = blockIdx.x * blockDim.x + threadIdx.x; // E*H
  if (i >= E_ * H_) return;
  int h = i & 3, e = i >> 2;
  int r = et[e];
  int n = dst[e];
  float v = q[(size_t)n * 32 + r * 4 + h] + kk[(size_t)src[e] * 32 + r * 4 + h];
  v = v >= 0.f ? v : 0.2f * v;
  alpha[i] = v;
  atomicMax(&nm[n * H_ + h], fenc(v));
}

// ---------------- exp + atomic sum; albuf <- exp(alpha - max) ----------------
__global__ void k_expsum(const int* __restrict__ dst, const u32* __restrict__ nm,
                         float* __restrict__ alpha, float* __restrict__ nd) {
  int i = blockIdx.x * blockDim.x + threadIdx.x; // E*H
  if (i >= E_ * H_) return;
  int h = i & 3, e = i >> 2;
  int n = dst[e];
  float ex = expf(alpha[i] - fdec(nm[n * H_ + h]));
  alpha[i] = ex;
  atomicAdd(&nd[n * H_ + h], ex);
}

// ---------------- fp32 -> bf16 conversions ----------------
__global__ void k_cvt_x(const float* __restrict__ x, u16* __restrict__ xb) {
  int i = blockIdx.x * blockDim.x + threadIdx.x; // N*D/4
  if (i >= N_ * D_ / 4) return;
  const float4 v = ((const float4*)x)[i];
  uint2 o;
  o.x = (u32)bfr(v.x) | ((u32)bfr(v.y) << 16);
  o.y = (u32)bfr(v.z) | ((u32)bfr(v.w) << 16);
  *(uint2*)&xb[(size_t)i * 4] = o;
}

// W[l] fp32 [R][D][HK] -> wt bf16 [R][HK][D]
__global__ void k_cvt_w(const float* __restrict__ Wl, u16* __restrict__ wt) {
  __shared__ u16 tile[64][65];
  const int r = blockIdx.z, k0 = blockIdx.y * 64, c0 = blockIdx.x * 64;
  const int t = threadIdx.x;
  const int tk = t >> 4, tc4 = (t & 15) * 4;
#pragma unroll
  for (int p = 0; p < 4; ++p) {
    int krow = tk + p * 16;
    const float4 v = *(const float4*)&Wl[((size_t)r * D_ + k0 + krow) * HK_ + c0 + tc4];
    tile[tc4 + 0][krow] = bfr(v.x);
    tile[tc4 + 1][krow] = bfr(v.y);
    tile[tc4 + 2][krow] = bfr(v.z);
    tile[tc4 + 3][krow] = bfr(v.w);
  }
  __syncthreads();
#pragma unroll
  for (int p = 0; p < 4; ++p) {
    int crow = tk + p * 16;
    uint2 o;
    o.x = (u32)tile[crow][tc4 + 0] | ((u32)tile[crow][tc4 + 1] << 16);
    o.y = (u32)tile[crow][tc4 + 2] | ((u32)tile[crow][tc4 + 3] << 16);
    *(uint2*)&wt[((size_t)r * HK_ + c0 + crow) * D_ + k0 + tc4] = o;
  }
}

// ---------------- MFMA GEMM -> bf16 y ----------------
// xb: [N][128] bf16, wt_r: [512][128] bf16, y16: [N][512] bf16
// Swapped-operand MFMA: acc lane holds 4 CONSECUTIVE columns -> packed 8B stores.
__global__ __launch_bounds__(256) void k_mfma(const u16* __restrict__ xb,
                                              const u16* __restrict__ wt,
                                              u16* __restrict__ y16) {
  __shared__ unsigned char lds[65536];  // A: 0..32KB, B: 32..64KB
  const int t = threadIdx.x;
  const int m0 = blockIdx.x * 128;
  const int c0 = blockIdx.y * 128;
#pragma unroll
  for (int p = 0; p < 8; ++p) {
    int idx = t + p * 256;
    int row = idx >> 4, seg = idx & 15;
    int lb = row * 256 + ((seg * 16) ^ ((row & 7) << 4));  // XOR swizzle
    uint4 va = *(const uint4*)(xb + (size_t)(m0 + row) * 128 + seg * 8);
    *(uint4*)(lds + lb) = va;
    uint4 vb = *(const uint4*)(wt + (size_t)(c0 + row) * 128 + seg * 8);
    *(uint4*)(lds + 32768 + lb) = vb;
  }
  __syncthreads();
  const int wid = t >> 6, lane = t & 63;
  const int wr = (wid >> 1) * 64, wc = (wid & 1) * 64;
  const int l15 = lane & 15, l4 = lane >> 4;
  f32x4 acc[4][4];
#pragma unroll
  for (int i = 0; i < 4; ++i)
#pragma unroll
    for (int j = 0; j < 4; ++j) acc[i][j] = (f32x4){0.f, 0.f, 0.f, 0.f};
#pragma unroll
  for (int ks = 0; ks < 4; ++ks) {
    short8 a[4], b[4];
#pragma unroll
    for (int i = 0; i < 4; ++i) {
      int row = wr + i * 16 + l15;
      int ko = (l4 * 16 + ks * 64) ^ ((row & 7) << 4);
      a[i] = *(const short8*)(lds + row * 256 + ko);
      int col = wc + i * 16 + l15;
      int ko2 = (l4 * 16 + ks * 64) ^ ((col & 7) << 4);
      b[i] = *(const short8*)(lds + 32768 + col * 256 + ko2);
    }
    // swapped operands: result is y^T fragment (lane = 1 row x 4 consecutive cols)
#pragma unroll
    for (int i = 0; i < 4; ++i)
#pragma unroll
      for (int j = 0; j < 4; ++j)
        acc[i][j] = __builtin_amdgcn_mfma_f32_16x16x32_bf16(b[j], a[i], acc[i][j], 0, 0, 0);
  }
  // lane holds y[m0+wr+i*16+l15][c0+wc+j*16+l4*4 .. +3]
#pragma unroll
  for (int i = 0; i < 4; ++i) {
    int row = m0 + wr + i * 16 + l15;
#pragma unroll
    for (int j = 0; j < 4; ++j) {
      int col = c0 + wc + j * 16 + l4 * 4;
      uint2 o;
      o.x = (u32)bfr(acc[i][j][0]) | ((u32)bfr(acc[i][j][1]) << 16);
      o.y = (u32)bfr(acc[i][j][2]) | ((u32)bfr(acc[i][j][3]) << 16);
      *(uint2*)(y16 + (size_t)row * HK_ + col) = o;
    }
  }
}

// ---------------- aggregation (one relation slice), fused softmax-normalize ----------------
__global__ __launch_bounds__(256) void k_agg(
    const int* __restrict__ ip, const int* __restrict__ es,
    const int* __restrict__ src, const float* __restrict__ a,
    const float* __restrict__ nd, const u16* __restrict__ y16,
    float* __restrict__ acc) {
  int n = blockIdx.x * 4 + (threadIdx.x >> 6);
  int lane = threadIdx.x & 63;
  int b = ip[n], e2 = ip[n + 1];
  if (b >= e2) return;
  float inv0 = 0.25f / (nd[n * 4 + 0] + 1e-16f);
  float inv1 = 0.25f / (nd[n * 4 + 1] + 1e-16f);
  float inv2 = 0.25f / (nd[n * 4 + 2] + 1e-16f);
  float inv3 = 0.25f / (nd[n * 4 + 3] + 1e-16f);
  float s0 = 0.f, s1 = 0.f;   // d = 2*lane, 2*lane+1
  for (int j = b; j < e2; ++j) {
    int e = es[j];
    int s = src[e];
    const u32* row = (const u32*)(y16 + (size_t)s * HK_);
    float w0 = a[e * 4 + 0] * inv0, w1 = a[e * 4 + 1] * inv1;
    float w2 = a[e * 4 + 2] * inv2, w3 = a[e * 4 + 3] * inv3;
    u32 v0 = row[0 * 64 + lane], v1 = row[1 * 64 + lane];
    u32 v2 = row[2 * 64 + lane], v3 = row[3 * 64 + lane];
    s0 += w0 * bf2f(v0 & 0xffffu) + w1 * bf2f(v1 & 0xffffu) +
          w2 * bf2f(v2 & 0xffffu) + w3 * bf2f(v3 & 0xffffu);
    s1 += w0 * bf2f(v0 >> 16) + w1 * bf2f(v1 >> 16) +
          w2 * bf2f(v2 >> 16) + w3 * bf2f(v3 >> 16);
  }
  float2* xp = (float2*)(acc + (size_t)n * D_) + lane;
  float2 v = *xp;
  v.x += s0; v.y += s1;
  *xp = v;
}

// ---------------- bias + relu ----------------
__global__ void k_bias_relu(float* __restrict__ x, const float* __restrict__ Bl) {
  int i = blockIdx.x * blockDim.x + threadIdx.x;
  if (i < N_ * D_) x[i] = fmaxf(x[i] + Bl[i & 127], 0.f);
}

// ---------------- graph mean-pool ----------------
__global__ void k_pool(const float* __restrict__ x, float* __restrict__ pooled) {
  int i = blockIdx.x * blockDim.x + threadIdx.x; // G*D
  if (i >= G_ * D_) return;
  int d = i & 127, g = i >> 7;
  float s = 0.f;
  for (int j = 0; j < NPG_; ++j) s += x[(size_t)(g * NPG_ + j) * D_ + d];
  pooled[i] = s * (1.0f / NPG_);
}

// ---------------- head MLP ----------------
__global__ void k_head(const float* __restrict__ pooled, const float* __restrict__ fc1w,
                       const float* __restrict__ fc1b, const float* __restrict__ polw,
                       const float* __restrict__ polb, const float* __restrict__ valw,
                       const float* __restrict__ valb, float* __restrict__ out) {
  int g = blockIdx.x;
  int t = threadIdx.x; // 64
  __shared__ float hb[64];
  const float* p = pooled + (size_t)g * D_;
  float s = fc1b[t];
  for (int d = 0; d < D_; ++d) s += p[d] * fc1w[d * 64 + t];
  hb[t] = fmaxf(s, 0.f);
  __syncthreads();
  if (t < 7) {
    float s2 = polb[t];
    for (int j = 0; j < 64; ++j) s2 += hb[j] * polw[j * 7 + t];
    out[g * 7 + t] = s2;
  } else if (t == 7) {
    float s2 = valb[0];
    for (int j = 0; j < 64; ++j) s2 += hb[j] * valw[j];
    out[G_ * 7 + g] = tanhf(s2);
  }
}

extern "C" void kernel_launch(void* const* d_in, const int* in_sizes, int n_in,
                              void* d_out, int out_size, void* d_ws, size_t ws_size,
                              hipStream_t stream) {
  (void)in_sizes; (void)n_in; (void)out_size;
  const int*   x_nodes = (const int*)d_in[0];
  const int*   eidx    = (const int*)d_in[1];
  const int*   etype   = (const int*)d_in[2];
  const float* emb     = (const float*)d_in[4];
  const float* W       = (const float*)d_in[5];
  const float* Q       = (const float*)d_in[6];
  const float* Km      = (const float*)d_in[7];
  const float* B       = (const float*)d_in[8];
  const float* fc1w    = (const float*)d_in[9];
  const float* fc1b    = (const float*)d_in[10];
  const float* polw    = (const float*)d_in[11];
  const float* polb    = (const float*)d_in[12];
  const float* valw    = (const float*)d_in[13];
  const float* valb    = (const float*)d_in[14];
  float* out = (float*)d_out;
  const int* srcA = eidx;        // edge_index[0,:]
  const int* dstA = eidx + E_;   // edge_index[1,:]

  char* p = (char*)d_ws;
  size_t used = 0;
  auto carve = [&](size_t bytes) {
    char* q = p;
    size_t adv = (bytes + 255) & ~(size_t)255;
    p += adv;
    used += adv;
    return q;
  };
  float* x_cur  = (float*)carve((size_t)N_ * D_ * 4);        // 10.5 MB
  float* x_nxt  = (float*)carve((size_t)N_ * D_ * 4);        // 10.5 MB
  u16*   ybuf   = (u16*)carve((size_t)N_ * HK_ * 2);         // 21.0 MB (bf16)
  float* qk_reg = (float*)carve((size_t)N_ * 64 * 4);        // 5.2 MB
  float* qbuf   = qk_reg;                                     // [N][32]
  float* kbuf   = qk_reg + (size_t)N_ * 32;                   // [N][32]
  u16*   xbf    = (u16*)qk_reg;                               // alias (q/k dead by cvt_x)
  float* albuf  = (float*)carve((size_t)E_ * H_ * 4);        // 2.6 MB
  u32*   nmb    = (u32*)carve((size_t)N_ * H_ * 4);
  float* ndb    = (float*)carve((size_t)N_ * H_ * 4);
  float* WQKb   = (float*)carve((size_t)D_ * 64 * 4);
  u16*   Wtb    = (u16*)carve((size_t)R_ * HK_ * D_ * 2);    // 1.05 MB
  float* pooled = (float*)carve((size_t)G_ * D_ * 4);
  int* countsR  = (int*)carve((size_t)R_ * N_ * 4);
  int* cursorR  = (int*)carve((size_t)R_ * N_ * 4);
  int* indptrR  = (int*)carve((size_t)(R_ * N_ + 1) * 4);
  int* esortR   = (int*)carve((size_t)E_ * 4);
  int* bsum     = (int*)carve((size_t)512 * 4);
  if (used > ws_size) return;  // defensive: fail via poisoned output, not OOB crash

  constexpr int RN = R_ * N_;          // 163840
  constexpr int NB = RN / 1024;        // 160 scan blocks

  // ---- rel-CSR build ----
  k_zero_i<<<(RN + 255) / 256, 256, 0, stream>>>(countsR, RN);
  k_count_rel<<<E_ / 256, 256, 0, stream>>>(dstA, etype, countsR);
  k_bsum<<<NB, 256, 0, stream>>>(countsR, bsum);
  k_bscan<<<1, 512, 0, stream>>>(bsum, NB, indptrR + RN);
  k_scan3<<<NB, 256, 0, stream>>>(countsR, bsum, indptrR, cursorR);
  k_scatter_rel<<<E_ / 256, 256, 0, stream>>>(dstA, etype, cursorR, esortR);
  k_embed<<<(N_ * D_) / 256, 256, 0, stream>>>(x_nodes, emb, x_cur);

  for (int l = 0; l < L_; ++l) {
    const float* Wl = W + (size_t)l * R_ * D_ * HK_;
    const float* Ql = Q + (size_t)l * HK_ * H_;
    const float* Kl = Km + (size_t)l * HK_ * H_;
    const float* Bl = B + (size_t)l * D_;
    // attention path (fp32)
    k_wqk<<<(D_ * 64) / 256, 256, 0, stream>>>(Wl, Ql, Kl, WQKb);
    k_qk<<<N_ / 32, 256, 0, stream>>>(x_cur, WQKb, qbuf, kbuf);
    k_zero_nmnd<<<(N_ * H_ + 255) / 256, 256, 0, stream>>>(nmb, ndb, N_ * H_);
    k_alpha_max<<<(E_ * H_) / 256, 256, 0, stream>>>(srcA, dstA, etype, qbuf, kbuf,
                                                     albuf, nmb);
    k_expsum<<<(E_ * H_) / 256, 256, 0, stream>>>(dstA, nmb, albuf, ndb);
    // transform + aggregate (bf16 MFMA; xbf aliases q/k which are dead now)
    k_cvt_x<<<(N_ * D_ / 4) / 256, 256, 0, stream>>>(x_cur, xbf);
    k_cvt_w<<<dim3(HK_ / 64, D_ / 64, R_), 256, 0, stream>>>(Wl, Wtb);
    k_zero_f<<<(N_ * D_) / 256, 256, 0, stream>>>(x_nxt, N_ * D_);
    for (int r = 0; r < R_; ++r) {
      k_mfma<<<dim3(N_ / 128, HK_ / 128), 256, 0, stream>>>(
          xbf, Wtb + (size_t)r * HK_ * D_, ybuf);
      k_agg<<<N_ / 4, 256, 0, stream>>>(indptrR + (size_t)r * N_, esortR, srcA,
                                        albuf, ndb, ybuf, x_nxt);
    }
    k_bias_relu<<<(N_ * D_) / 256, 256, 0, stream>>>(x_nxt, Bl);
    float* tmp = x_cur; x_cur = x_nxt; x_nxt = tmp;
  }

  k_pool<<<(G_ * D_) / 256, 256, 0, stream>>>(x_cur, pooled);
  k_head<<<G_, 64, 0, stream>>>(pooled, fc1w, fc1b, polw, polb, valw, valb, out);
}

// Round 5
// 622.770 us; speedup vs baseline: 5.0108x; 1.7779x over previous
//
#include <hip/hip_runtime.h>
#include <cstdint>
#include <cstddef>

constexpr int N_  = 20480;
constexpr int E_  = 163840;
constexpr int G_  = 512;
constexpr int D_  = 128;
constexpr int H_  = 4;
constexpr int R_  = 8;
constexpr int L_  = 4;
constexpr int HK_ = 512;   // H*D
constexpr int NPG_ = N_ / G_; // 40

typedef short short8 __attribute__((ext_vector_type(8)));
typedef float f32x4 __attribute__((ext_vector_type(4)));
typedef unsigned short u16;
typedef unsigned int u32;

__device__ inline u16 bfr(float f) {  // fp32 -> bf16 RNE
  u32 u = __builtin_bit_cast(u32, f);
  return (u16)((u + 0x7fffu + ((u >> 16) & 1u)) >> 16);
}
__device__ inline float bf2f(u32 lo16) { return __builtin_bit_cast(float, lo16 << 16); }
// order-preserving float<->uint encode for atomicMax (enc(x) > 0 for all finite x)
__device__ inline u32 fenc(float f) {
  u32 u = __builtin_bit_cast(u32, f);
  return (u & 0x80000000u) ? ~u : (u | 0x80000000u);
}
__device__ inline float fdec(u32 k) {
  u32 u = (k & 0x80000000u) ? (k ^ 0x80000000u) : ~k;
  return __builtin_bit_cast(float, u);
}

// ---------------- zero helpers ----------------
__global__ void k_zero_i(int* __restrict__ p, int n) {
  int i = blockIdx.x * blockDim.x + threadIdx.x;
  if (i < n) p[i] = 0;
}
__global__ void k_zero_nmnd(u32* __restrict__ nm, float* __restrict__ nd, int n) {
  int i = blockIdx.x * blockDim.x + threadIdx.x;
  if (i < n) { nm[i] = 0u; nd[i] = 0.f; }   // enc 0 == "-inf" sentinel
}

// ---------------- dst-CSR build ----------------
__global__ void k_count_dst(const int* __restrict__ dst, int* __restrict__ counts) {
  int e = blockIdx.x * blockDim.x + threadIdx.x;
  if (e < E_) atomicAdd(&counts[dst[e]], 1);
}
// phase 1: per-block (1024 items) sums
__global__ void k_bsum(const int* __restrict__ c, int* __restrict__ bsum) {
  int t = threadIdx.x;
  const int4 v = *(const int4*)&c[blockIdx.x * 1024 + t * 4];
  int s = v.x + v.y + v.z + v.w;
#pragma unroll
  for (int o = 32; o; o >>= 1) s += __shfl_down(s, o, 64);
  __shared__ int ws_[4];
  if ((t & 63) == 0) ws_[t >> 6] = s;
  __syncthreads();
  if (t == 0) bsum[blockIdx.x] = ws_[0] + ws_[1] + ws_[2] + ws_[3];
}
// phase 2: exclusive scan of nb (<=512) block sums
__global__ void k_bscan(int* __restrict__ bsum, int nb, int* __restrict__ tot_out) {
  __shared__ int sh[512];
  int t = threadIdx.x;
  if (t < nb) sh[t] = bsum[t];
  __syncthreads();
  if (t == 0) {
    int run = 0;
    for (int i = 0; i < nb; ++i) { int v = sh[i]; sh[i] = run; run += v; }
    tot_out[0] = run;
  }
  __syncthreads();
  if (t < nb) bsum[t] = sh[t];
}
// phase 3: full exclusive scan write (indptr + cursor)
__global__ void k_scan3(const int* __restrict__ c, const int* __restrict__ bsum,
                        int* __restrict__ indptr, int* __restrict__ cursor) {
  __shared__ int ts[256];
  int t = threadIdx.x;
  int base = blockIdx.x * 1024 + t * 4;
  const int4 v = *(const int4*)&c[base];
  int s0 = v.x, s01 = v.x + v.y, s012 = s01 + v.z, s = s012 + v.w;
  ts[t] = s;
  __syncthreads();
#pragma unroll
  for (int o = 1; o < 256; o <<= 1) {
    int add = (t >= o) ? ts[t - o] : 0;
    __syncthreads();
    ts[t] += add;
    __syncthreads();
  }
  int off = bsum[blockIdx.x] + (t ? ts[t - 1] : 0);
  int4 o4 = make_int4(off, off + s0, off + s01, off + s012);
  *(int4*)&indptr[base] = o4;
  *(int4*)&cursor[base] = o4;
}
__global__ void k_scatter_dst(const int* __restrict__ dst, int* __restrict__ cursor,
                              int* __restrict__ esort) {
  int e = blockIdx.x * blockDim.x + threadIdx.x;
  if (e < E_) {
    int p = atomicAdd(&cursor[dst[e]], 1);
    esort[p] = e;
  }
}

// ---------------- embedding lookup ----------------
__global__ void k_embed(const int* __restrict__ xn, const float* __restrict__ emb,
                        float* __restrict__ x) {
  int i = blockIdx.x * blockDim.x + threadIdx.x;
  if (i < N_ * D_) {
    int n = i >> 7, d = i & 127;
    x[i] = emb[xn[n] * D_ + d];
  }
}

// ---------------- WQK for ALL layers: wave per (l,r,d) row ----------------
// WQK[l][d][c]: c = isK*32 + r*4 + h
__global__ __launch_bounds__(256) void k_wqk_all(const float* __restrict__ W,
                                                 const float* __restrict__ Q,
                                                 const float* __restrict__ Km,
                                                 float* __restrict__ WQK) {
  int gw = (blockIdx.x * 256 + threadIdx.x) >> 6;  // 0..L*R*D-1 = 4095
  int lane = threadIdx.x & 63;
  int d = gw & 127, r = (gw >> 7) & 7, l = gw >> 10;
  const float* wrow = W + (((size_t)l * R_ + r) * D_ + d) * HK_;
  const float* Ql = Q + (size_t)l * HK_ * H_;
  const float* Kl = Km + (size_t)l * HK_ * H_;
  float acc[8] = {0.f, 0.f, 0.f, 0.f, 0.f, 0.f, 0.f, 0.f};
#pragma unroll
  for (int it = 0; it < 8; ++it) {
    int k = it * 64 + lane;
    float w = wrow[k];
    const float4 qv = *(const float4*)&Ql[k * 4];
    const float4 kv = *(const float4*)&Kl[k * 4];
    acc[0] += w * qv.x; acc[1] += w * qv.y; acc[2] += w * qv.z; acc[3] += w * qv.w;
    acc[4] += w * kv.x; acc[5] += w * kv.y; acc[6] += w * kv.z; acc[7] += w * kv.w;
  }
#pragma unroll
  for (int o = 32; o; o >>= 1)
#pragma unroll
    for (int j = 0; j < 8; ++j) acc[j] += __shfl_down(acc[j], o, 64);
  if (lane == 0) {
#pragma unroll
    for (int h = 0; h < 4; ++h) {
      WQK[((size_t)l * D_ + d) * 64 + r * 4 + h] = acc[h];
      WQK[((size_t)l * D_ + d) * 64 + 32 + r * 4 + h] = acc[4 + h];
    }
  }
}

// ---------------- q,k: LDS-tiled small GEMM (32 nodes/block) ----------------
__global__ __launch_bounds__(256) void k_qk(const float* __restrict__ x,
                                            const float* __restrict__ WQK,
                                            float* __restrict__ q,
                                            float* __restrict__ kk) {
  __shared__ float xs[32][129];
  __shared__ float wq[128][64];
  const int t = threadIdx.x;
  const int n0 = blockIdx.x * 32;
#pragma unroll
  for (int p = 0; p < 4; ++p) {
    int idx = t + p * 256;
    int row = idx >> 5, c4 = (idx & 31) * 4;
    const float4 v = *(const float4*)&x[(size_t)(n0 + row) * D_ + c4];
    xs[row][c4 + 0] = v.x; xs[row][c4 + 1] = v.y;
    xs[row][c4 + 2] = v.z; xs[row][c4 + 3] = v.w;
  }
#pragma unroll
  for (int p = 0; p < 8; ++p) {
    int idx = t + p * 256;
    int row = idx >> 4, c4 = (idx & 15) * 4;
    *(float4*)&wq[row][c4] = *(const float4*)&WQK[row * 64 + c4];
  }
  __syncthreads();
  const int node = t >> 3, cq = t & 7;
  float s[8];
#pragma unroll
  for (int j = 0; j < 8; ++j) s[j] = 0.f;
  for (int k = 0; k < 128; ++k) {
    float xv = xs[node][k];
#pragma unroll
    for (int j = 0; j < 8; ++j) s[j] = fmaf(xv, wq[k][cq * 8 + j], s[j]);
  }
#pragma unroll
  for (int j = 0; j < 8; ++j) {
    int c = cq * 8 + j;
    if (c < 32) q[(size_t)(n0 + node) * 32 + c] = s[j];
    else        kk[(size_t)(n0 + node) * 32 + (c - 32)] = s[j];
  }
}

// ---------------- per-edge logits + atomic max ----------------
__global__ void k_alpha_max(const int* __restrict__ src, const int* __restrict__ dst,
                            const int* __restrict__ et, const float* __restrict__ q,
                            const float* __restrict__ kk, float* __restrict__ alpha,
                            u32* __restrict__ nm) {
  int i = blockIdx.x * blockDim.x + threadIdx.x; // E*H
  if (i >= E_ * H_) return;
  int h = i & 3, e = i >> 2;
  int r = et[e];
  int n = dst[e];
  float v = q[(size_t)n * 32 + r * 4 + h] + kk[(size_t)src[e] * 32 + r * 4 + h];
  v = v >= 0.f ? v : 0.2f * v;
  alpha[i] = v;
  atomicMax(&nm[n * H_ + h], fenc(v));
}

// ---------------- exp + atomic sum; albuf <- exp(alpha - max) ----------------
__global__ void k_expsum(const int* __restrict__ dst, const u32* __restrict__ nm,
                         float* __restrict__ alpha, float* __restrict__ nd) {
  int i = blockIdx.x * blockDim.x + threadIdx.x; // E*H
  if (i >= E_ * H_) return;
  int h = i & 3, e = i >> 2;
  int n = dst[e];
  float ex = expf(alpha[i] - fdec(nm[n * H_ + h]));
  alpha[i] = ex;
  atomicAdd(&nd[n * H_ + h], ex);
}

// ---------------- fp32 -> bf16 x ----------------
__global__ void k_cvt_x(const float* __restrict__ x, u16* __restrict__ xb) {
  int i = blockIdx.x * blockDim.x + threadIdx.x; // N*D/4
  if (i >= N_ * D_ / 4) return;
  const float4 v = ((const float4*)x)[i];
  uint2 o;
  o.x = (u32)bfr(v.x) | ((u32)bfr(v.y) << 16);
  o.y = (u32)bfr(v.z) | ((u32)bfr(v.w) << 16);
  *(uint2*)&xb[(size_t)i * 4] = o;
}

// W fp32 [L][R][D][HK] -> wt bf16 [L][R][HK][D]  (all layers, z = l*R+r)
__global__ void k_cvt_w_all(const float* __restrict__ W, u16* __restrict__ wt) {
  __shared__ u16 tile[64][65];
  const int z = blockIdx.z, k0 = blockIdx.y * 64, c0 = blockIdx.x * 64;
  const int t = threadIdx.x;
  const int tk = t >> 4, tc4 = (t & 15) * 4;
  const float* Wz = W + (size_t)z * D_ * HK_;
  u16* wz = wt + (size_t)z * HK_ * D_;
#pragma unroll
  for (int p = 0; p < 4; ++p) {
    int krow = tk + p * 16;
    const float4 v = *(const float4*)&Wz[(size_t)(k0 + krow) * HK_ + c0 + tc4];
    tile[tc4 + 0][krow] = bfr(v.x);
    tile[tc4 + 1][krow] = bfr(v.y);
    tile[tc4 + 2][krow] = bfr(v.z);
    tile[tc4 + 3][krow] = bfr(v.w);
  }
  __syncthreads();
#pragma unroll
  for (int p = 0; p < 4; ++p) {
    int crow = tk + p * 16;
    uint2 o;
    o.x = (u32)tile[crow][tc4 + 0] | ((u32)tile[crow][tc4 + 1] << 16);
    o.y = (u32)tile[crow][tc4 + 2] | ((u32)tile[crow][tc4 + 3] << 16);
    *(uint2*)&wz[(size_t)(c0 + crow) * D_ + k0 + tc4] = o;
  }
}

// ---------------- MFMA GEMM, all relations (z = r) -> y_all bf16 ----------------
// xb: [N][128] bf16, wt: [R][512][128] bf16 (layer base), y_all: [R][N][512] bf16
__global__ __launch_bounds__(256) void k_mfma(const u16* __restrict__ xb,
                                              const u16* __restrict__ wt,
                                              u16* __restrict__ y_all) {
  __shared__ unsigned char lds[65536];  // A: 0..32KB, B: 32..64KB
  const int t = threadIdx.x;
  const int m0 = blockIdx.x * 128;
  const int c0 = blockIdx.y * 128;
  const u16* wtr = wt + (size_t)blockIdx.z * HK_ * D_;
  u16* y16 = y_all + (size_t)blockIdx.z * N_ * HK_;
#pragma unroll
  for (int p = 0; p < 8; ++p) {
    int idx = t + p * 256;
    int row = idx >> 4, seg = idx & 15;
    int lb = row * 256 + ((seg * 16) ^ ((row & 7) << 4));  // XOR swizzle
    uint4 va = *(const uint4*)(xb + (size_t)(m0 + row) * 128 + seg * 8);
    *(uint4*)(lds + lb) = va;
    uint4 vb = *(const uint4*)(wtr + (size_t)(c0 + row) * 128 + seg * 8);
    *(uint4*)(lds + 32768 + lb) = vb;
  }
  __syncthreads();
  const int wid = t >> 6, lane = t & 63;
  const int wr = (wid >> 1) * 64, wc = (wid & 1) * 64;
  const int l15 = lane & 15, l4 = lane >> 4;
  f32x4 acc[4][4];
#pragma unroll
  for (int i = 0; i < 4; ++i)
#pragma unroll
    for (int j = 0; j < 4; ++j) acc[i][j] = (f32x4){0.f, 0.f, 0.f, 0.f};
#pragma unroll
  for (int ks = 0; ks < 4; ++ks) {
    short8 a[4], b[4];
#pragma unroll
    for (int i = 0; i < 4; ++i) {
      int row = wr + i * 16 + l15;
      int ko = (l4 * 16 + ks * 64) ^ ((row & 7) << 4);
      a[i] = *(const short8*)(lds + row * 256 + ko);
      int col = wc + i * 16 + l15;
      int ko2 = (l4 * 16 + ks * 64) ^ ((col & 7) << 4);
      b[i] = *(const short8*)(lds + 32768 + col * 256 + ko2);
    }
    // swapped operands: lane holds 1 row x 4 consecutive cols -> packed 8B stores
#pragma unroll
    for (int i = 0; i < 4; ++i)
#pragma unroll
      for (int j = 0; j < 4; ++j)
        acc[i][j] = __builtin_amdgcn_mfma_f32_16x16x32_bf16(b[j], a[i], acc[i][j], 0, 0, 0);
  }
#pragma unroll
  for (int i = 0; i < 4; ++i) {
    int row = m0 + wr + i * 16 + l15;
#pragma unroll
    for (int j = 0; j < 4; ++j) {
      int col = c0 + wc + j * 16 + l4 * 4;
      uint2 o;
      o.x = (u32)bfr(acc[i][j][0]) | ((u32)bfr(acc[i][j][1]) << 16);
      o.y = (u32)bfr(acc[i][j][2]) | ((u32)bfr(acc[i][j][3]) << 16);
      *(uint2*)(y16 + (size_t)row * HK_ + col) = o;
    }
  }
}

// ---------------- aggregation, all relations via dst-CSR; fused bias+relu ----------------
__global__ __launch_bounds__(256) void k_agg_all(
    const int* __restrict__ ip, const int* __restrict__ es,
    const int* __restrict__ src, const int* __restrict__ et,
    const float* __restrict__ a, const float* __restrict__ nd,
    const u16* __restrict__ y_all, const float* __restrict__ Bl,
    float* __restrict__ xout) {
  int n = blockIdx.x * 4 + (threadIdx.x >> 6);
  int lane = threadIdx.x & 63;
  int b = ip[n], e2 = ip[n + 1];
  float inv0 = 0.25f / (nd[n * 4 + 0] + 1e-16f);
  float inv1 = 0.25f / (nd[n * 4 + 1] + 1e-16f);
  float inv2 = 0.25f / (nd[n * 4 + 2] + 1e-16f);
  float inv3 = 0.25f / (nd[n * 4 + 3] + 1e-16f);
  float s0 = 0.f, s1 = 0.f;   // d = 2*lane, 2*lane+1
  for (int j = b; j < e2; ++j) {
    int e = es[j];
    int s = src[e];
    int r = et[e];
    const u32* row = (const u32*)(y_all + ((size_t)r * N_ + s) * HK_);
    float w0 = a[e * 4 + 0] * inv0, w1 = a[e * 4 + 1] * inv1;
    float w2 = a[e * 4 + 2] * inv2, w3 = a[e * 4 + 3] * inv3;
    u32 v0 = row[0 * 64 + lane], v1 = row[1 * 64 + lane];
    u32 v2 = row[2 * 64 + lane], v3 = row[3 * 64 + lane];
    s0 += w0 * bf2f(v0 & 0xffffu) + w1 * bf2f(v1 & 0xffffu) +
          w2 * bf2f(v2 & 0xffffu) + w3 * bf2f(v3 & 0xffffu);
    s1 += w0 * bf2f(v0 >> 16) + w1 * bf2f(v1 >> 16) +
          w2 * bf2f(v2 >> 16) + w3 * bf2f(v3 >> 16);
  }
  float2 o;
  o.x = fmaxf(s0 + Bl[2 * lane], 0.f);
  o.y = fmaxf(s1 + Bl[2 * lane + 1], 0.f);
  *((float2*)(xout + (size_t)n * D_) + lane) = o;
}

// ---------------- graph mean-pool ----------------
__global__ void k_pool(const float* __restrict__ x, float* __restrict__ pooled) {
  int i = blockIdx.x * blockDim.x + threadIdx.x; // G*D
  if (i >= G_ * D_) return;
  int d = i & 127, g = i >> 7;
  float s = 0.f;
  for (int j = 0; j < NPG_; ++j) s += x[(size_t)(g * NPG_ + j) * D_ + d];
  pooled[i] = s * (1.0f / NPG_);
}

// ---------------- head MLP ----------------
__global__ void k_head(const float* __restrict__ pooled, const float* __restrict__ fc1w,
                       const float* __restrict__ fc1b, const float* __restrict__ polw,
                       const float* __restrict__ polb, const float* __restrict__ valw,
                       const float* __restrict__ valb, float* __restrict__ out) {
  int g = blockIdx.x;
  int t = threadIdx.x; // 64
  __shared__ float hb[64];
  const float* p = pooled + (size_t)g * D_;
  float s = fc1b[t];
  for (int d = 0; d < D_; ++d) s += p[d] * fc1w[d * 64 + t];
  hb[t] = fmaxf(s, 0.f);
  __syncthreads();
  if (t < 7) {
    float s2 = polb[t];
    for (int j = 0; j < 64; ++j) s2 += hb[j] * polw[j * 7 + t];
    out[g * 7 + t] = s2;
  } else if (t == 7) {
    float s2 = valb[0];
    for (int j = 0; j < 64; ++j) s2 += hb[j] * valw[j];
    out[G_ * 7 + g] = tanhf(s2);
  }
}

extern "C" void kernel_launch(void* const* d_in, const int* in_sizes, int n_in,
                              void* d_out, int out_size, void* d_ws, size_t ws_size,
                              hipStream_t stream) {
  (void)in_sizes; (void)n_in; (void)out_size;
  const int*   x_nodes = (const int*)d_in[0];
  const int*   eidx    = (const int*)d_in[1];
  const int*   etype   = (const int*)d_in[2];
  const float* emb     = (const float*)d_in[4];
  const float* W       = (const float*)d_in[5];
  const float* Q       = (const float*)d_in[6];
  const float* Km      = (const float*)d_in[7];
  const float* B       = (const float*)d_in[8];
  const float* fc1w    = (const float*)d_in[9];
  const float* fc1b    = (const float*)d_in[10];
  const float* polw    = (const float*)d_in[11];
  const float* polb    = (const float*)d_in[12];
  const float* valw    = (const float*)d_in[13];
  const float* valb    = (const float*)d_in[14];
  float* out = (float*)d_out;
  const int* srcA = eidx;        // edge_index[0,:]
  const int* dstA = eidx + E_;   // edge_index[1,:]

  char* p = (char*)d_ws;
  size_t used = 0;
  auto carve = [&](size_t bytes) {
    char* q = p;
    size_t adv = (bytes + 255) & ~(size_t)255;
    p += adv;
    used += adv;
    return q;
  };
  float* x_cur  = (float*)carve((size_t)N_ * D_ * 4);            // 10.5 MB
  float* x_nxt  = (float*)carve((size_t)N_ * D_ * 4);            // 10.5 MB
  u16*   y_all  = (u16*)carve((size_t)R_ * N_ * HK_ * 2);        // 167.8 MB
  float* qk_reg = (float*)carve((size_t)N_ * 64 * 4);            // 5.2 MB
  float* qbuf   = qk_reg;                                         // [N][32]
  float* kbuf   = qk_reg + (size_t)N_ * 32;                       // [N][32]
  u16*   xbf    = (u16*)qk_reg;                                   // alias (q/k dead by cvt_x)
  float* albuf  = (float*)carve((size_t)E_ * H_ * 4);            // 2.6 MB
  u32*   nmb    = (u32*)carve((size_t)N_ * H_ * 4);
  float* ndb    = (float*)carve((size_t)N_ * H_ * 4);
  float* WQKb   = (float*)carve((size_t)L_ * D_ * 64 * 4);       // 131 KB (all layers)
  u16*   Wtb    = (u16*)carve((size_t)L_ * R_ * HK_ * D_ * 2);   // 4.2 MB (all layers)
  float* pooled = (float*)carve((size_t)G_ * D_ * 4);
  int* countsN  = (int*)carve((size_t)N_ * 4);
  int* cursorN  = (int*)carve((size_t)N_ * 4);
  int* indptrN  = (int*)carve((size_t)(N_ + 1) * 4);
  int* esortD   = (int*)carve((size_t)E_ * 4);
  int* bsum     = (int*)carve((size_t)512 * 4);
  if (used > ws_size) return;  // defensive: fail via poisoned output, not OOB crash

  constexpr int NB = N_ / 1024;  // 20 scan blocks

  // ---- dst-CSR build + one-time precomputes ----
  k_zero_i<<<(N_ + 255) / 256, 256, 0, stream>>>(countsN, N_);
  k_count_dst<<<E_ / 256, 256, 0, stream>>>(dstA, countsN);
  k_bsum<<<NB, 256, 0, stream>>>(countsN, bsum);
  k_bscan<<<1, 512, 0, stream>>>(bsum, NB, indptrN + N_);
  k_scan3<<<NB, 256, 0, stream>>>(countsN, bsum, indptrN, cursorN);
  k_scatter_dst<<<E_ / 256, 256, 0, stream>>>(dstA, cursorN, esortD);
  k_embed<<<(N_ * D_) / 256, 256, 0, stream>>>(x_nodes, emb, x_cur);
  k_wqk_all<<<(L_ * R_ * D_ * 64) / 256, 256, 0, stream>>>(W, Q, Km, WQKb);
  k_cvt_w_all<<<dim3(HK_ / 64, D_ / 64, L_ * R_), 256, 0, stream>>>(W, Wtb);

  for (int l = 0; l < L_; ++l) {
    const float* Bl = B + (size_t)l * D_;
    // attention path (fp32)
    k_qk<<<N_ / 32, 256, 0, stream>>>(x_cur, WQKb + (size_t)l * D_ * 64, qbuf, kbuf);
    k_zero_nmnd<<<(N_ * H_ + 255) / 256, 256, 0, stream>>>(nmb, ndb, N_ * H_);
    k_alpha_max<<<(E_ * H_) / 256, 256, 0, stream>>>(srcA, dstA, etype, qbuf, kbuf,
                                                     albuf, nmb);
    k_expsum<<<(E_ * H_) / 256, 256, 0, stream>>>(dstA, nmb, albuf, ndb);
    // transform all relations in one dispatch (xbf aliases q/k, dead now)
    k_cvt_x<<<(N_ * D_ / 4) / 256, 256, 0, stream>>>(x_cur, xbf);
    k_mfma<<<dim3(N_ / 128, HK_ / 128, R_), 256, 0, stream>>>(
        xbf, Wtb + (size_t)l * R_ * HK_ * D_, y_all);
    // aggregate all relations in one pass; fused bias+relu
    k_agg_all<<<N_ / 4, 256, 0, stream>>>(indptrN, esortD, srcA, etype, albuf, ndb,
                                          y_all, Bl, x_nxt);
    float* tmp = x_cur; x_cur = x_nxt; x_nxt = tmp;
  }

  k_pool<<<(G_ * D_) / 256, 256, 0, stream>>>(x_cur, pooled);
  k_head<<<G_, 64, 0, stream>>>(pooled, fc1w, fc1b, polw, polb, valw, valb, out);
}

// Round 7
// 616.162 us; speedup vs baseline: 5.0645x; 1.0107x over previous
//
#include <hip/hip_runtime.h>
#include <cstdint>
#include <cstddef>

constexpr int N_  = 20480;
constexpr int E_  = 163840;
constexpr int G_  = 512;
constexpr int D_  = 128;
constexpr int H_  = 4;
constexpr int R_  = 8;
constexpr int L_  = 4;
constexpr int HK_ = 512;   // H*D
constexpr int NPG_ = N_ / G_; // 40

typedef short short8 __attribute__((ext_vector_type(8)));
typedef float f32x4 __attribute__((ext_vector_type(4)));
typedef unsigned short u16;
typedef unsigned int u32;

__device__ inline u16 bfr(float f) {  // fp32 -> bf16 RNE
  u32 u = __builtin_bit_cast(u32, f);
  return (u16)((u + 0x7fffu + ((u >> 16) & 1u)) >> 16);
}
__device__ inline float bf2f(u32 lo16) { return __builtin_bit_cast(float, lo16 << 16); }
// order-preserving float<->uint encode for atomicMax (enc(x) > 0 for all finite x)
__device__ inline u32 fenc(float f) {
  u32 u = __builtin_bit_cast(u32, f);
  return (u & 0x80000000u) ? ~u : (u | 0x80000000u);
}
__device__ inline float fdec(u32 k) {
  u32 u = (k & 0x80000000u) ? (k ^ 0x80000000u) : ~k;
  return __builtin_bit_cast(float, u);
}

// ---------------- zero helpers ----------------
__global__ void k_zero_i(int* __restrict__ p, int n) {
  int i = blockIdx.x * blockDim.x + threadIdx.x;
  if (i < n) p[i] = 0;
}
__global__ void k_zero_nmnd(u32* __restrict__ nm, float* __restrict__ nd, int n) {
  int i = blockIdx.x * blockDim.x + threadIdx.x;
  if (i < n) { nm[i] = 0u; nd[i] = 0.f; }   // enc 0 == "-inf" sentinel
}

// ---------------- rel-CSR build (edges keyed by r*N+dst) ----------------
__global__ void k_count_rel(const int* __restrict__ dst, const int* __restrict__ et,
                            int* __restrict__ counts) {
  int e = blockIdx.x * blockDim.x + threadIdx.x;
  if (e < E_) atomicAdd(&counts[et[e] * N_ + dst[e]], 1);
}
// phase 1: per-block (1024 items) sums
__global__ void k_bsum(const int* __restrict__ c, int* __restrict__ bsum) {
  int t = threadIdx.x;
  const int4 v = *(const int4*)&c[blockIdx.x * 1024 + t * 4];
  int s = v.x + v.y + v.z + v.w;
#pragma unroll
  for (int o = 32; o; o >>= 1) s += __shfl_down(s, o, 64);
  __shared__ int ws_[4];
  if ((t & 63) == 0) ws_[t >> 6] = s;
  __syncthreads();
  if (t == 0) bsum[blockIdx.x] = ws_[0] + ws_[1] + ws_[2] + ws_[3];
}
// phase 2: exclusive scan of nb (<=512) block sums; ALSO writes grand total
// (BUG FIX r6: round-6 dropped tot_out, leaving indptrR[R*N] uninitialized ->
//  padBase[R_] poison -> every k_edge block early-returned -> zero output.)
__global__ void k_bscan(int* __restrict__ bsum, int nb, int* __restrict__ tot_out) {
  __shared__ int sh[512];
  int t = threadIdx.x;
  if (t < nb) sh[t] = bsum[t];
  __syncthreads();
  if (t == 0) {
    int run = 0;
    for (int i = 0; i < nb; ++i) { int v = sh[i]; sh[i] = run; run += v; }
    tot_out[0] = run;
  }
  __syncthreads();
  if (t < nb) bsum[t] = sh[t];
}
// phase 3: full exclusive scan write (indptr + cursor)
__global__ void k_scan3(const int* __restrict__ c, const int* __restrict__ bsum,
                        int* __restrict__ indptr, int* __restrict__ cursor) {
  __shared__ int ts[256];
  int t = threadIdx.x;
  int base = blockIdx.x * 1024 + t * 4;
  const int4 v = *(const int4*)&c[base];
  int s0 = v.x, s01 = v.x + v.y, s012 = s01 + v.z, s = s012 + v.w;
  ts[t] = s;
  __syncthreads();
#pragma unroll
  for (int o = 1; o < 256; o <<= 1) {
    int add = (t >= o) ? ts[t - o] : 0;
    __syncthreads();
    ts[t] += add;
    __syncthreads();
  }
  int off = bsum[blockIdx.x] + (t ? ts[t - 1] : 0);
  int4 o4 = make_int4(off, off + s0, off + s01, off + s012);
  *(int4*)&indptr[base] = o4;
  *(int4*)&cursor[base] = o4;
}
__global__ void k_scatter_rel(const int* __restrict__ dst, const int* __restrict__ et,
                              int* __restrict__ cursor, int* __restrict__ esort) {
  int e = blockIdx.x * blockDim.x + threadIdx.x;
  if (e < E_) {
    int p = atomicAdd(&cursor[et[e] * N_ + dst[e]], 1);
    esort[p] = e;
  }
}
// padded (to 64) per-relation bases, in edge-slot units
__global__ void k_padbase(const int* __restrict__ indptrR, int* __restrict__ padBase) {
  if (threadIdx.x == 0 && blockIdx.x == 0) {
    int cum = 0;
    for (int r = 0; r < R_; ++r) {
      padBase[r] = cum;
      int cnt = indptrR[(r + 1) * N_] - indptrR[r * N_];
      cum += (cnt + 63) & ~63;
    }
    padBase[R_] = cum;
  }
}

// ---------------- embedding lookup ----------------
__global__ void k_embed(const int* __restrict__ xn, const float* __restrict__ emb,
                        float* __restrict__ x) {
  int i = blockIdx.x * blockDim.x + threadIdx.x;
  if (i < N_ * D_) {
    int n = i >> 7, d = i & 127;
    x[i] = emb[xn[n] * D_ + d];
  }
}

// ---------------- WQK for ALL layers: wave per (l,r,d) row ----------------
__global__ __launch_bounds__(256) void k_wqk_all(const float* __restrict__ W,
                                                 const float* __restrict__ Q,
                                                 const float* __restrict__ Km,
                                                 float* __restrict__ WQK) {
  int gw = (blockIdx.x * 256 + threadIdx.x) >> 6;  // 0..L*R*D-1 = 4095
  int lane = threadIdx.x & 63;
  int d = gw & 127, r = (gw >> 7) & 7, l = gw >> 10;
  const float* wrow = W + (((size_t)l * R_ + r) * D_ + d) * HK_;
  const float* Ql = Q + (size_t)l * HK_ * H_;
  const float* Kl = Km + (size_t)l * HK_ * H_;
  float acc[8] = {0.f, 0.f, 0.f, 0.f, 0.f, 0.f, 0.f, 0.f};
#pragma unroll
  for (int it = 0; it < 8; ++it) {
    int k = it * 64 + lane;
    float w = wrow[k];
    const float4 qv = *(const float4*)&Ql[k * 4];
    const float4 kv = *(const float4*)&Kl[k * 4];
    acc[0] += w * qv.x; acc[1] += w * qv.y; acc[2] += w * qv.z; acc[3] += w * qv.w;
    acc[4] += w * kv.x; acc[5] += w * kv.y; acc[6] += w * kv.z; acc[7] += w * kv.w;
  }
#pragma unroll
  for (int o = 32; o; o >>= 1)
#pragma unroll
    for (int j = 0; j < 8; ++j) acc[j] += __shfl_down(acc[j], o, 64);
  if (lane == 0) {
#pragma unroll
    for (int h = 0; h < 4; ++h) {
      WQK[((size_t)l * D_ + d) * 64 + r * 4 + h] = acc[h];
      WQK[((size_t)l * D_ + d) * 64 + 32 + r * 4 + h] = acc[4 + h];
    }
  }
}

// ---------------- q,k: LDS-tiled small GEMM (32 nodes/block) ----------------
__global__ __launch_bounds__(256) void k_qk(const float* __restrict__ x,
                                            const float* __restrict__ WQK,
                                            float* __restrict__ q,
                                            float* __restrict__ kk) {
  __shared__ float xs[32][129];
  __shared__ float wq[128][64];
  const int t = threadIdx.x;
  const int n0 = blockIdx.x * 32;
#pragma unroll
  for (int p = 0; p < 4; ++p) {
    int idx = t + p * 256;
    int row = idx >> 5, c4 = (idx & 31) * 4;
    const float4 v = *(const float4*)&x[(size_t)(n0 + row) * D_ + c4];
    xs[row][c4 + 0] = v.x; xs[row][c4 + 1] = v.y;
    xs[row][c4 + 2] = v.z; xs[row][c4 + 3] = v.w;
  }
#pragma unroll
  for (int p = 0; p < 8; ++p) {
    int idx = t + p * 256;
    int row = idx >> 4, c4 = (idx & 15) * 4;
    *(float4*)&wq[row][c4] = *(const float4*)&WQK[row * 64 + c4];
  }
  __syncthreads();
  const int node = t >> 3, cq = t & 7;
  float s[8];
#pragma unroll
  for (int j = 0; j < 8; ++j) s[j] = 0.f;
  for (int k = 0; k < 128; ++k) {
    float xv = xs[node][k];
#pragma unroll
    for (int j = 0; j < 8; ++j) s[j] = fmaf(xv, wq[k][cq * 8 + j], s[j]);
  }
#pragma unroll
  for (int j = 0; j < 8; ++j) {
    int c = cq * 8 + j;
    if (c < 32) q[(size_t)(n0 + node) * 32 + c] = s[j];
    else        kk[(size_t)(n0 + node) * 32 + (c - 32)] = s[j];
  }
}

// ---------------- per-edge logits + atomic max ----------------
__global__ void k_alpha_max(const int* __restrict__ src, const int* __restrict__ dst,
                            const int* __restrict__ et, const float* __restrict__ q,
                            const float* __restrict__ kk, float* __restrict__ alpha,
                            u32* __restrict__ nm) {
  int i = blockIdx.x * blockDim.x + threadIdx.x; // E*H
  if (i >= E_ * H_) return;
  int h = i & 3, e = i >> 2;
  int r = et[e];
  int n = dst[e];
  float v = q[(size_t)n * 32 + r * 4 + h] + kk[(size_t)src[e] * 32 + r * 4 + h];
  v = v >= 0.f ? v : 0.2f * v;
  alpha[i] = v;
  atomicMax(&nm[n * H_ + h], fenc(v));
}

// ---------------- exp + atomic sum; albuf <- exp(alpha - max) ----------------
__global__ void k_expsum(const int* __restrict__ dst, const u32* __restrict__ nm,
                         float* __restrict__ alpha, float* __restrict__ nd) {
  int i = blockIdx.x * blockDim.x + threadIdx.x; // E*H
  if (i >= E_ * H_) return;
  int h = i & 3, e = i >> 2;
  int n = dst[e];
  float ex = expf(alpha[i] - fdec(nm[n * H_ + h]));
  alpha[i] = ex;
  atomicAdd(&nd[n * H_ + h], ex);
}

// ---------------- fp32 -> bf16 x ----------------
__global__ void k_cvt_x(const float* __restrict__ x, u16* __restrict__ xb) {
  int i = blockIdx.x * blockDim.x + threadIdx.x; // N*D/4
  if (i >= N_ * D_ / 4) return;
  const float4 v = ((const float4*)x)[i];
  uint2 o;
  o.x = (u32)bfr(v.x) | ((u32)bfr(v.y) << 16);
  o.y = (u32)bfr(v.z) | ((u32)bfr(v.w) << 16);
  *(uint2*)&xb[(size_t)i * 4] = o;
}

// W fp32 [L][R][D][HK] -> wt bf16 [L][R][HK][D]  (all layers, z = l*R+r)
__global__ void k_cvt_w_all(const float* __restrict__ W, u16* __restrict__ wt) {
  __shared__ u16 tile[64][65];
  const int z = blockIdx.z, k0 = blockIdx.y * 64, c0 = blockIdx.x * 64;
  const int t = threadIdx.x;
  const int tk = t >> 4, tc4 = (t & 15) * 4;
  const float* Wz = W + (size_t)z * D_ * HK_;
  u16* wz = wt + (size_t)z * HK_ * D_;
#pragma unroll
  for (int p = 0; p < 4; ++p) {
    int krow = tk + p * 16;
    const float4 v = *(const float4*)&Wz[(size_t)(k0 + krow) * HK_ + c0 + tc4];
    tile[tc4 + 0][krow] = bfr(v.x);
    tile[tc4 + 1][krow] = bfr(v.y);
    tile[tc4 + 2][krow] = bfr(v.z);
    tile[tc4 + 3][krow] = bfr(v.w);
  }
  __syncthreads();
#pragma unroll
  for (int p = 0; p < 4; ++p) {
    int crow = tk + p * 16;
    uint2 o;
    o.x = (u32)tile[crow][tc4 + 0] | ((u32)tile[crow][tc4 + 1] << 16);
    o.y = (u32)tile[crow][tc4 + 2] | ((u32)tile[crow][tc4 + 3] << 16);
    *(uint2*)&wz[(size_t)(c0 + crow) * D_ + k0 + tc4] = o;
  }
}

// ---------------- edge-GEMM: m[e,d] = sum_h a'[e,h] * (x[src]@W[r])[h*128+d] ----------------
// 64 edges/block (rel-sorted, padded to 64 per relation). Wave w owns edge rows
// w*16..w*16+15 x all 512 cols; head-reduce is in-register (cols j, j+8h same lane).
__global__ __launch_bounds__(256) void k_edge(
    const u16* __restrict__ xb, const u16* __restrict__ wt,   // wt: layer base [R][HK][D]
    const int* __restrict__ esortR, const int* __restrict__ indptrR,
    const int* __restrict__ padBase,
    const int* __restrict__ src, const int* __restrict__ dst,
    const float* __restrict__ a, const float* __restrict__ nd,
    u16* __restrict__ m) {
  __shared__ u16 atile[64 * 128];      // 16 KB, swizzled
  __shared__ u16 bks[512 * 32];        // 32 KB, swizzled
  __shared__ float awl[64][4];
  __shared__ int srcl[64];
  const int t = threadIdx.x;
  const int b64 = blockIdx.x * 64;
  if (b64 >= padBase[R_]) return;      // block-uniform
  int r = 0;
  while (b64 >= padBase[r + 1]) ++r;   // block-uniform
  const int ip0 = indptrR[r * N_];
  const int cnt = indptrR[(r + 1) * N_] - ip0;
  const int local0 = b64 - padBase[r];
  if (t < 64) {
    int lidx = local0 + t;
    if (lidx < cnt) {
      int e = esortR[ip0 + lidx];
      int n = dst[e];
      srcl[t] = src[e];
#pragma unroll
      for (int h = 0; h < 4; ++h)
        awl[t][h] = a[e * 4 + h] * 0.25f / (nd[n * 4 + h] + 1e-16f);
    } else {
      srcl[t] = 0;
      awl[t][0] = awl[t][1] = awl[t][2] = awl[t][3] = 0.f;
    }
  }
  __syncthreads();
  // A tile: 64 gathered rows x 256 B, XOR-swizzled
#pragma unroll
  for (int p = 0; p < 4; ++p) {
    int idx = t + p * 256;
    int row = idx >> 4, seg = idx & 15;
    uint4 v = *(const uint4*)(xb + (size_t)srcl[row] * 128 + seg * 8);
    *(uint4*)((char*)atile + row * 256 + ((seg * 16) ^ ((row & 7) << 4))) = v;
  }
  const int wid = t >> 6, lane = t & 63;
  const int l15 = lane & 15, l4 = lane >> 4;
  const int myrow = wid * 16 + l15;
  const u16* wrp = wt + (size_t)r * HK_ * D_;
  f32x4 acc[32];
#pragma unroll
  for (int j = 0; j < 32; ++j) acc[j] = (f32x4){0.f, 0.f, 0.f, 0.f};
  for (int ks = 0; ks < 4; ++ks) {
    __syncthreads();   // protect bks from previous iteration / finish A writes
    // stage B chunk [512 c][32 k] bf16 = 32 KB, swizzled on k-seg by ((c>>1)&3)
#pragma unroll
    for (int p = 0; p < 8; ++p) {
      int idx = t + p * 256;
      int c = idx >> 2, s = idx & 3;
      uint4 v = *(const uint4*)(wrp + (size_t)c * 128 + ks * 32 + s * 8);
      *(uint4*)((char*)bks + c * 64 + ((s * 16) ^ (((c >> 1) & 3) << 4))) = v;
    }
    __syncthreads();
    const short8 av = *(const short8*)((char*)atile + myrow * 256 +
                        ((l4 * 16 + ks * 64) ^ ((myrow & 7) << 4)));
#pragma unroll
    for (int j = 0; j < 32; ++j) {
      int c = j * 16 + l15;
      const short8 bv = *(const short8*)((char*)bks + c * 64 +
                          ((l4 * 16) ^ (((c >> 1) & 3) << 4)));
      // swapped operands: lane holds row=myrow (edge), cols j*16 + l4*4 + rg
      acc[j] = __builtin_amdgcn_mfma_f32_16x16x32_bf16(bv, av, acc[j], 0, 0, 0);
    }
  }
  // epilogue: in-register head reduction (head h = col>>7 lives at frag j+8h)
  const float aw0 = awl[myrow][0], aw1 = awl[myrow][1];
  const float aw2 = awl[myrow][2], aw3 = awl[myrow][3];
  u16* mrow = m + (size_t)(b64 + myrow) * 128;
#pragma unroll
  for (int jj = 0; jj < 8; ++jj) {
    float v0 = aw0 * acc[jj][0] + aw1 * acc[jj + 8][0] + aw2 * acc[jj + 16][0] + aw3 * acc[jj + 24][0];
    float v1 = aw0 * acc[jj][1] + aw1 * acc[jj + 8][1] + aw2 * acc[jj + 16][1] + aw3 * acc[jj + 24][1];
    float v2 = aw0 * acc[jj][2] + aw1 * acc[jj + 8][2] + aw2 * acc[jj + 16][2] + aw3 * acc[jj + 24][2];
    float v3 = aw0 * acc[jj][3] + aw1 * acc[jj + 8][3] + aw2 * acc[jj + 16][3] + aw3 * acc[jj + 24][3];
    uint2 o;
    o.x = (u32)bfr(v0) | ((u32)bfr(v1) << 16);
    o.y = (u32)bfr(v2) | ((u32)bfr(v3) << 16);
    *(uint2*)(mrow + jj * 16 + l4 * 4) = o;
  }
}

// ---------------- aggregation: wave per dst node over 8 relation segments ----------------
__global__ __launch_bounds__(256) void k_agg2(
    const int* __restrict__ indptrR, const int* __restrict__ padBase,
    const u16* __restrict__ m, const float* __restrict__ Bl,
    float* __restrict__ xout) {
  int n = blockIdx.x * 4 + (threadIdx.x >> 6);
  int lane = threadIdx.x & 63;
  float s0 = 0.f, s1 = 0.f;   // d = 2*lane, 2*lane+1
#pragma unroll
  for (int r = 0; r < R_; ++r) {
    int ip0 = indptrR[r * N_];
    int j0 = indptrR[r * N_ + n], j1 = indptrR[r * N_ + n + 1];
    int base = padBase[r] + (j0 - ip0);
    for (int j = 0; j < j1 - j0; ++j) {
      u32 v = *((const u32*)(m + (size_t)(base + j) * 128) + lane);
      s0 += bf2f(v & 0xffffu);
      s1 += bf2f(v >> 16);
    }
  }
  float2 o;
  o.x = fmaxf(s0 + Bl[2 * lane], 0.f);
  o.y = fmaxf(s1 + Bl[2 * lane + 1], 0.f);
  *((float2*)(xout + (size_t)n * D_) + lane) = o;
}

// ---------------- graph mean-pool ----------------
__global__ void k_pool(const float* __restrict__ x, float* __restrict__ pooled) {
  int i = blockIdx.x * blockDim.x + threadIdx.x; // G*D
  if (i >= G_ * D_) return;
  int d = i & 127, g = i >> 7;
  float s = 0.f;
  for (int j = 0; j < NPG_; ++j) s += x[(size_t)(g * NPG_ + j) * D_ + d];
  pooled[i] = s * (1.0f / NPG_);
}

// ---------------- head MLP ----------------
__global__ void k_head(const float* __restrict__ pooled, const float* __restrict__ fc1w,
                       const float* __restrict__ fc1b, const float* __restrict__ polw,
                       const float* __restrict__ polb, const float* __restrict__ valw,
                       const float* __restrict__ valb, float* __restrict__ out) {
  int g = blockIdx.x;
  int t = threadIdx.x; // 64
  __shared__ float hb[64];
  const float* p = pooled + (size_t)g * D_;
  float s = fc1b[t];
  for (int d = 0; d < D_; ++d) s += p[d] * fc1w[d * 64 + t];
  hb[t] = fmaxf(s, 0.f);
  __syncthreads();
  if (t < 7) {
    float s2 = polb[t];
    for (int j = 0; j < 64; ++j) s2 += hb[j] * polw[j * 7 + t];
    out[g * 7 + t] = s2;
  } else if (t == 7) {
    float s2 = valb[0];
    for (int j = 0; j < 64; ++j) s2 += hb[j] * valw[j];
    out[G_ * 7 + g] = tanhf(s2);
  }
}

extern "C" void kernel_launch(void* const* d_in, const int* in_sizes, int n_in,
                              void* d_out, int out_size, void* d_ws, size_t ws_size,
                              hipStream_t stream) {
  (void)in_sizes; (void)n_in; (void)out_size;
  const int*   x_nodes = (const int*)d_in[0];
  const int*   eidx    = (const int*)d_in[1];
  const int*   etype   = (const int*)d_in[2];
  const float* emb     = (const float*)d_in[4];
  const float* W       = (const float*)d_in[5];
  const float* Q       = (const float*)d_in[6];
  const float* Km      = (const float*)d_in[7];
  const float* B       = (const float*)d_in[8];
  const float* fc1w    = (const float*)d_in[9];
  const float* fc1b    = (const float*)d_in[10];
  const float* polw    = (const float*)d_in[11];
  const float* polb    = (const float*)d_in[12];
  const float* valw    = (const float*)d_in[13];
  const float* valb    = (const float*)d_in[14];
  float* out = (float*)d_out;
  const int* srcA = eidx;        // edge_index[0,:]
  const int* dstA = eidx + E_;   // edge_index[1,:]

  char* p = (char*)d_ws;
  size_t used = 0;
  auto carve = [&](size_t bytes) {
    char* q = p;
    size_t adv = (bytes + 255) & ~(size_t)255;
    p += adv;
    used += adv;
    return q;
  };
  float* x_cur  = (float*)carve((size_t)N_ * D_ * 4);            // 10.5 MB
  float* x_nxt  = (float*)carve((size_t)N_ * D_ * 4);            // 10.5 MB
  u16*   mbuf   = (u16*)carve((size_t)(E_ + 512) * D_ * 2);      // 42.1 MB
  float* qk_reg = (float*)carve((size_t)N_ * 64 * 4);            // 5.2 MB
  float* qbuf   = qk_reg;                                         // [N][32]
  float* kbuf   = qk_reg + (size_t)N_ * 32;                       // [N][32]
  u16*   xbf    = (u16*)qk_reg;                                   // alias (q/k dead by cvt_x)
  float* albuf  = (float*)carve((size_t)E_ * H_ * 4);            // 2.6 MB
  u32*   nmb    = (u32*)carve((size_t)N_ * H_ * 4);
  float* ndb    = (float*)carve((size_t)N_ * H_ * 4);
  float* WQKb   = (float*)carve((size_t)L_ * D_ * 64 * 4);       // 131 KB
  u16*   Wtb    = (u16*)carve((size_t)L_ * R_ * HK_ * D_ * 2);   // 4.2 MB
  float* pooled = (float*)carve((size_t)G_ * D_ * 4);
  int* countsR  = (int*)carve((size_t)R_ * N_ * 4);              // 0.66 MB
  int* cursorR  = (int*)carve((size_t)R_ * N_ * 4);
  int* indptrR  = (int*)carve((size_t)(R_ * N_ + 1) * 4);
  int* esortR   = (int*)carve((size_t)E_ * 4);
  int* padBase  = (int*)carve((size_t)(R_ + 1) * 4);
  int* bsum     = (int*)carve((size_t)512 * 4);
  if (used > ws_size) return;  // defensive: fail via poisoned output, not OOB crash

  constexpr int RN = R_ * N_;          // 163840
  constexpr int NB = RN / 1024;        // 160 scan blocks
  constexpr int EDGE_BLOCKS = E_ / 64 + R_;  // 2568 (upper bound incl. padding)

  // ---- rel-CSR build + one-time precomputes ----
  k_zero_i<<<(RN + 255) / 256, 256, 0, stream>>>(countsR, RN);
  k_count_rel<<<E_ / 256, 256, 0, stream>>>(dstA, etype, countsR);
  k_bsum<<<NB, 256, 0, stream>>>(countsR, bsum);
  k_bscan<<<1, 512, 0, stream>>>(bsum, NB, indptrR + RN);  // writes indptrR[RN]=E
  k_scan3<<<NB, 256, 0, stream>>>(countsR, bsum, indptrR, cursorR);
  k_scatter_rel<<<E_ / 256, 256, 0, stream>>>(dstA, etype, cursorR, esortR);
  k_padbase<<<1, 64, 0, stream>>>(indptrR, padBase);
  k_embed<<<(N_ * D_) / 256, 256, 0, stream>>>(x_nodes, emb, x_cur);
  k_wqk_all<<<(L_ * R_ * D_ * 64) / 256, 256, 0, stream>>>(W, Q, Km, WQKb);
  k_cvt_w_all<<<dim3(HK_ / 64, D_ / 64, L_ * R_), 256, 0, stream>>>(W, Wtb);

  for (int l = 0; l < L_; ++l) {
    const float* Bl = B + (size_t)l * D_;
    // attention path (fp32)
    k_qk<<<N_ / 32, 256, 0, stream>>>(x_cur, WQKb + (size_t)l * D_ * 64, qbuf, kbuf);
    k_zero_nmnd<<<(N_ * H_ + 255) / 256, 256, 0, stream>>>(nmb, ndb, N_ * H_);
    k_alpha_max<<<(E_ * H_) / 256, 256, 0, stream>>>(srcA, dstA, etype, qbuf, kbuf,
                                                     albuf, nmb);
    k_expsum<<<(E_ * H_) / 256, 256, 0, stream>>>(dstA, nmb, albuf, ndb);
    // per-edge weighted messages via MFMA (head-reduced in epilogue)
    k_cvt_x<<<(N_ * D_ / 4) / 256, 256, 0, stream>>>(x_cur, xbf);
    k_edge<<<EDGE_BLOCKS, 256, 0, stream>>>(xbf, Wtb + (size_t)l * R_ * HK_ * D_,
                                            esortR, indptrR, padBase, srcA, dstA,
                                            albuf, ndb, mbuf);
    // per-dst sum of contiguous message rows; fused bias+relu
    k_agg2<<<N_ / 4, 256, 0, stream>>>(indptrR, padBase, mbuf, Bl, x_nxt);
    float* tmp = x_cur; x_cur = x_nxt; x_nxt = tmp;
  }

  k_pool<<<(G_ * D_) / 256, 256, 0, stream>>>(x_cur, pooled);
  k_head<<<G_, 64, 0, stream>>>(pooled, fc1w, fc1b, polw, polb, valw, valb, out);
}